// Round 2
// baseline (161.692 us; speedup 1.0000x reference)
//
#include <hip/hip_runtime.h>

// Problem constants
#define BATCH 2
#define LSEQ 384
#define NHID 512
#define NH 8
#define DH 64
#define BH (BATCH*NH)          // 16
#define XELEMS ((size_t)768 * NHID)        // 393216 (x output elems)
#define TQ 8                   // q-rows per attn block
#define QTILES (LSEQ/TQ)       // 48

typedef unsigned short ushort_t;
typedef __attribute__((ext_vector_type(8))) short bf16x8;
typedef __attribute__((ext_vector_type(4))) float f32x4;

__device__ __forceinline__ float bf2f(ushort_t u) {
    unsigned int v = ((unsigned int)u) << 16;
    return __uint_as_float(v);
}
__device__ __forceinline__ ushort_t f2bf(float f) {
    unsigned int u = __float_as_uint(f);
    unsigned int lsb = (u >> 16) & 1u;
    u += 0x7fffu + lsb;           // round-to-nearest-even
    return (ushort_t)(u >> 16);
}
// RNE bf16 pair-pack: 2x add + v_perm (ushort0=bf16(a), ushort1=bf16(b))
__device__ __forceinline__ unsigned pk_bf16(float a, float b) {
    unsigned ua = __float_as_uint(a), ub = __float_as_uint(b);
    ua += 0x7fffu + ((ua >> 16) & 1u);
    ub += 0x7fffu + ((ub >> 16) & 1u);
    return __builtin_amdgcn_perm(ub, ua, 0x07060302);
}
__device__ __forceinline__ float ld1(const void* p, size_t i, int f) {
    return f ? ((const float*)p)[i] : bf2f(((const ushort_t*)p)[i]);
}
__device__ __forceinline__ float4 ld4(const void* p, size_t i, int f) {
    if (f) return ((const float4*)p)[i >> 2];
    ushort4 u = ((const ushort4*)p)[i >> 2];
    return make_float4(bf2f(u.x), bf2f(u.y), bf2f(u.z), bf2f(u.w));
}
__device__ __forceinline__ int block_detect(const unsigned int* q, int* cnt) {
    int t = threadIdx.x;
    if (t == 0) *cnt = 0;
    __syncthreads();
    int n = blockDim.x < 256 ? blockDim.x : 256;
    if (t < n) {
        unsigned int elo = (q[t] >> 7) & 0xFFu;
        if (elo >= 100u && elo <= 150u) atomicAdd(cnt, 1);
    }
    __syncthreads();
    return (*cnt * 2 > n) ? 0 : 1;     // 0 = bf16-packed, 1 = fp32
}
__device__ __forceinline__ uint4 packu4(float4 a, float4 b) {
    uint4 r;
    r.x = pk_bf16(a.x, a.y); r.y = pk_bf16(a.z, a.w);
    r.z = pk_bf16(b.x, b.y); r.w = pk_bf16(b.z, b.w);
    return r;
}
__device__ __forceinline__ bf16x8 pack_bf8(float4 a, float4 b) {
    union { uint4 u; bf16x8 v; } r;
    r.u = packu4(a, b);
    return r.v;
}

// ---------------- workspace layout (float offsets) ----------------
#define OFF_ETQ   16                  // Etq = exp(2 tq)  [bh][l][d]
#define OFF_ETK   (16 + 393216)       // Etk = exp(2 tk)  [bh][l][d] (row-major)
#define OFF_VH    (16 + 2*393216)     // V                [bh][l][d]
#define OFF_XH    (16 + 3*393216)     // context [B,L,H,D]

#define LDSTR 72   // LDS row stride in ushorts (144 B)

// ---------------------------------------------------------------------------
// Kernel 1: QKV projection via bf16 MFMA. 32(m) x 64(n=head) tile.
// r15: in-block split-K x2 — 256 thr (4 waves); waves{0,1}=K[0,256),
// waves{2,3}=K[256,512), each half double-staged in its own LDS buffer.
// K-loop 8->4 iters (latency-bound critical path halves), waves/SIMD 2x.
// Cross-half reduce via padded sred[32][65]; fold/epilogue gated to kh==0.
// Modes 0/1 fold W1/W2 via a second in-register MFMA pass and write
// Etq/Etk = exp(2(..+biasF)) row-major; mode 2 writes V + bv.
// ---------------------------------------------------------------------------
__global__ __launch_bounds__(256) void gemm_qkv(
    const void* qp, const void* kp, const void* vp,
    const void* Wqp, const void* Wkp, const void* Wvp,
    const void* W1p, const void* W2p,
    const void* bqp, const void* bkp, const void* b1p, const void* b2p,
    const void* bvp, float* __restrict__ ws)
{
    __shared__ int s_cnt;
    __shared__ ushort_t smA[2][32 * LDSTR];
    __shared__ ushort_t smB[2][64 * LDSTR];
    __shared__ float sred[32][65];
    __shared__ float biasF[64];
    const int f = block_detect((const unsigned int*)qp, &s_cnt);

    const int mode = blockIdx.z;
    const void* A = (mode == 0) ? qp : (mode == 1) ? kp : vp;
    const void* W = (mode == 0) ? Wqp : (mode == 1) ? Wkp : Wvp;
    const void* W1x = (mode == 1) ? W2p : W1p;

    const int h    = blockIdx.x;
    const int col0 = h * 64;
    const int row0 = blockIdx.y * 32;
    const int t = threadIdx.x;
    const int th = t & 127;        // lane within k-half
    const int kh = t >> 7;         // which k-half
    const int w2 = (t >> 6) & 1;   // wave within k-half (row group)
    const int l16 = t & 15, quad = (t & 63) >> 4;

    // fused bias into LDS (threads 0..63), overlapped with prefetch
    if (t < 64) {
        if (mode == 2) {
            biasF[t] = ld1(bvp, col0 + t, f);
        } else {
            const void* b1x = (mode == 1) ? b2p : b1p;
            const void* bx  = (mode == 1) ? bkp : bqp;
            float s = ld1(b1x, t, f);
            for (int j = 0; j < 64; j++)
                s = fmaf(ld1(W1x, (size_t)t * 64 + j, f), ld1(bx, h * 64 + j, f), s);
            biasF[t] = s;
        }
    }

    const int arow = th >> 2, acol = (th & 3) * 16;
    const int brow = th >> 1, bcol = (th & 1) * 32;
    const size_t abase = (size_t)(row0 + arow) * 512 + kh * 256 + acol;
    const size_t bbase = (size_t)(col0 + brow) * 512 + kh * 256 + bcol;

    float4 a4[4], b4[8];
    #pragma unroll
    for (int i = 0; i < 4; i++) a4[i] = ld4(A, abase + i * 4, f);
    #pragma unroll
    for (int i = 0; i < 8; i++) b4[i] = ld4(W, bbase + i * 4, f);

    f32x4 acc[4];
    #pragma unroll
    for (int nt = 0; nt < 4; nt++) acc[nt] = (f32x4){0.f, 0.f, 0.f, 0.f};

    for (int k0 = 0; k0 < 256; k0 += 64) {
        __syncthreads();
        *reinterpret_cast<uint4*>(&smA[kh][arow * LDSTR + acol])     = packu4(a4[0], a4[1]);
        *reinterpret_cast<uint4*>(&smA[kh][arow * LDSTR + acol + 8]) = packu4(a4[2], a4[3]);
        *reinterpret_cast<uint4*>(&smB[kh][brow * LDSTR + bcol])      = packu4(b4[0], b4[1]);
        *reinterpret_cast<uint4*>(&smB[kh][brow * LDSTR + bcol + 8])  = packu4(b4[2], b4[3]);
        *reinterpret_cast<uint4*>(&smB[kh][brow * LDSTR + bcol + 16]) = packu4(b4[4], b4[5]);
        *reinterpret_cast<uint4*>(&smB[kh][brow * LDSTR + bcol + 24]) = packu4(b4[6], b4[7]);
        __syncthreads();
        if (k0 + 64 < 256) {
            #pragma unroll
            for (int i = 0; i < 4; i++) a4[i] = ld4(A, abase + k0 + 64 + i * 4, f);
            #pragma unroll
            for (int i = 0; i < 8; i++) b4[i] = ld4(W, bbase + k0 + 64 + i * 4, f);
        }
        #pragma unroll
        for (int kk = 0; kk < 2; kk++) {
            bf16x8 af = *reinterpret_cast<const bf16x8*>(
                &smA[kh][(w2 * 16 + l16) * LDSTR + kk * 32 + quad * 8]);
            #pragma unroll
            for (int nt = 0; nt < 4; nt++) {
                bf16x8 bfr = *reinterpret_cast<const bf16x8*>(
                    &smB[kh][(nt * 16 + l16) * LDSTR + kk * 32 + quad * 8]);
                acc[nt] = __builtin_amdgcn_mfma_f32_16x16x32_bf16(af, bfr, acc[nt], 0, 0, 0);
            }
        }
    }

    // ---- cross-half reduction (K[256:512) partial -> K[0:256) waves) ----
    if (kh == 1) {
        #pragma unroll
        for (int nt = 0; nt < 4; nt++)
            #pragma unroll
            for (int r = 0; r < 4; r++)
                sred[w2 * 16 + quad * 4 + r][nt * 16 + l16] = acc[nt][r];
    }
    __syncthreads();
    if (kh == 0) {
        #pragma unroll
        for (int nt = 0; nt < 4; nt++)
            #pragma unroll
            for (int r = 0; r < 4; r++)
                acc[nt][r] += sred[w2 * 16 + quad * 4 + r][nt * 16 + l16];

        const int b  = (row0 >= LSEQ) ? 1 : 0;
        const int lbase = row0 - b * LSEQ + w2 * 16;
        const int bh = b * NH + h;

        if (mode == 2) {
            float* Out = ws + OFF_VH;
            #pragma unroll
            for (int nt = 0; nt < 4; nt++) {
                int d = l16 + nt * 16;
                float bi = biasF[d];
                #pragma unroll
                for (int r = 0; r < 4; r++) {
                    int l = lbase + quad * 4 + r;
                    Out[(size_t)(bh * LSEQ + l) * 64 + d] = acc[nt][r] + bi;
                }
            }
        } else {
            // ---- fold: restage acc (bf16) in wave-private LDS rows, x W1^T ----
            #pragma unroll
            for (int nt = 0; nt < 4; nt++)
                #pragma unroll
                for (int r = 0; r < 4; r++)
                    smA[0][(w2 * 16 + quad * 4 + r) * LDSTR + l16 + nt * 16] =
                        f2bf(acc[nt][r]);
            f32x4 acc2[4];
            #pragma unroll
            for (int nt = 0; nt < 4; nt++) acc2[nt] = (f32x4){0.f, 0.f, 0.f, 0.f};
            #pragma unroll
            for (int kk = 0; kk < 2; kk++) {
                bf16x8 af2 = *reinterpret_cast<const bf16x8*>(
                    &smA[0][(w2 * 16 + l16) * LDSTR + kk * 32 + quad * 8]);
                #pragma unroll
                for (int nt = 0; nt < 4; nt++) {
                    int od = nt * 16 + l16, j0 = kk * 32 + quad * 8;
                    float4 wa = ld4(W1x, (size_t)od * 64 + j0, f);
                    float4 wb = ld4(W1x, (size_t)od * 64 + j0 + 4, f);
                    bf16x8 bfw = pack_bf8(wa, wb);
                    acc2[nt] = __builtin_amdgcn_mfma_f32_16x16x32_bf16(af2, bfw, acc2[nt], 0, 0, 0);
                }
            }
            float* Out = ws + ((mode == 0) ? OFF_ETQ : OFF_ETK);   // both row-major
            #pragma unroll
            for (int nt = 0; nt < 4; nt++) {
                int d = l16 + nt * 16;
                float bi = biasF[d];
                #pragma unroll
                for (int r = 0; r < 4; r++) {
                    int l = lbase + quad * 4 + r;
                    Out[(size_t)(bh * LSEQ + l) * 64 + d] =
                        __expf(2.f * (acc2[nt][r] + bi));
                }
            }
        }
    }
}

// ---------------------------------------------------------------------------
// Kernel 2: additive attention, TQ=8, 384 threads (t = k). Etk row-major:
// thread t reads its Etk row via 16 b128 loads (deep MLP, L1 reuse).
// Energy (r14): PAIRED reciprocals with pre-scaled operands. Instead of
//   e2 += w_d * rcp(Etq*Etk + 1)           (1 rcp per d — trans-pipe bound,
//                                            v_rcp_f32 is quarter-rate)
// we precompute Etq' = Etq/w_d, c_d = 1/w_d so u_d = fma(Etq',Ek,c_d)
//   = (x_d+1)/w_d, and per PAIR: 1/u1 + 1/u2 = (u1+u2)*rcp(u1*u2).
// Per d: main pipe 5 cyc vs trans 4 (was main 4 / trans 8) → ~1.6x energy.
// NOTE (r13 post-mortem): do NOT add per-thread arrays to the energy loop —
// under __launch_bounds__(384,6) they spill to scratch (372 MB FETCH, 3x dur).
// ---------------------------------------------------------------------------
__global__ __launch_bounds__(384, 6) void attn_kernel(
    const void* qp, const void* vwp, const void* vbp,
    const float* __restrict__ ws_in, float* __restrict__ ws,
    const int* __restrict__ mask, void* __restrict__ dout)
{
    __shared__ int s_cnt;
    const int f = block_detect((const unsigned int*)qp, &s_cnt);

    const float* Etq = ws_in + OFF_ETQ;
    const float* Etk = ws_in + OFF_ETK;
    const float* Vh  = ws_in + OFF_VH;
    float* Xh = ws + OFF_XH;

    const int bid = blockIdx.x;
    const int qt = bid % QTILES;
    const int bh = bid / QTILES;
    const int q0 = qt * TQ;
    const int b  = bh >> 3;
    const int h  = bh & 7;
    const int t  = threadIdx.x;
    const int wave = t >> 6;

    __shared__ __align__(16) float etq8[64][TQ];   // Etq / w_d
    __shared__ float cws[64];                       // 1 / w_d
    __shared__ float ps[TQ][LSEQ];
    __shared__ float red[6][TQ][16][4];
    __shared__ float rsum[TQ][6];
    __shared__ float s_vb;

    for (int i = t; i < TQ * 64; i += 384) {
        int qi = i >> 6, d = i & 63;
        float wv = ld1(vwp, d, f);
        etq8[d][qi] = Etq[(size_t)(bh * LSEQ + q0 + qi) * 64 + d] / wv;
    }
    if (t < 64) {
        float v = ld1(vwp, t, f);
        cws[t] = 1.0f / v;
        #pragma unroll
        for (int off = 32; off > 0; off >>= 1) v += __shfl_xor(v, off, 64);
        if (t == 0) s_vb = ld1(vbp, 0, f) + v;
    }
    const int mok = mask[b * LSEQ + t];
    __syncthreads();
    const float vbSum = s_vb;

    float e2[TQ] = {0.f, 0.f, 0.f, 0.f, 0.f, 0.f, 0.f, 0.f};
    const float* ekrow = Etk + (size_t)(bh * LSEQ + t) * 64;
    #pragma unroll 2
    for (int dv = 0; dv < 16; dv++) {
        float4 ek4 = *reinterpret_cast<const float4*>(ekrow + dv * 4);
        #pragma unroll
        for (int pj = 0; pj < 2; pj++) {
            const int d0 = dv * 4 + pj * 2;
            const float ekA = pj ? ek4.z : ek4.x;
            const float ekB = pj ? ek4.w : ek4.y;
            const float cA = cws[d0];
            const float cB = cws[d0 + 1];
            float4 qA0 = *reinterpret_cast<const float4*>(&etq8[d0][0]);
            float4 qA1 = *reinterpret_cast<const float4*>(&etq8[d0][4]);
            float4 qB0 = *reinterpret_cast<const float4*>(&etq8[d0 + 1][0]);
            float4 qB1 = *reinterpret_cast<const float4*>(&etq8[d0 + 1][4]);
            {
                float u1 = fmaf(qA0.x, ekA, cA), u2 = fmaf(qB0.x, ekB, cB);
                e2[0] = fmaf(u1 + u2, __builtin_amdgcn_rcpf(u1 * u2), e2[0]);
            }
            {
                float u1 = fmaf(qA0.y, ekA, cA), u2 = fmaf(qB0.y, ekB, cB);
                e2[1] = fmaf(u1 + u2, __builtin_amdgcn_rcpf(u1 * u2), e2[1]);
            }
            {
                float u1 = fmaf(qA0.z, ekA, cA), u2 = fmaf(qB0.z, ekB, cB);
                e2[2] = fmaf(u1 + u2, __builtin_amdgcn_rcpf(u1 * u2), e2[2]);
            }
            {
                float u1 = fmaf(qA0.w, ekA, cA), u2 = fmaf(qB0.w, ekB, cB);
                e2[3] = fmaf(u1 + u2, __builtin_amdgcn_rcpf(u1 * u2), e2[3]);
            }
            {
                float u1 = fmaf(qA1.x, ekA, cA), u2 = fmaf(qB1.x, ekB, cB);
                e2[4] = fmaf(u1 + u2, __builtin_amdgcn_rcpf(u1 * u2), e2[4]);
            }
            {
                float u1 = fmaf(qA1.y, ekA, cA), u2 = fmaf(qB1.y, ekB, cB);
                e2[5] = fmaf(u1 + u2, __builtin_amdgcn_rcpf(u1 * u2), e2[5]);
            }
            {
                float u1 = fmaf(qA1.z, ekA, cA), u2 = fmaf(qB1.z, ekB, cB);
                e2[6] = fmaf(u1 + u2, __builtin_amdgcn_rcpf(u1 * u2), e2[6]);
            }
            {
                float u1 = fmaf(qA1.w, ekA, cA), u2 = fmaf(qB1.w, ekB, cB);
                e2[7] = fmaf(u1 + u2, __builtin_amdgcn_rcpf(u1 * u2), e2[7]);
            }
        }
    }

    float p[TQ];
    #pragma unroll
    for (int qi = 0; qi < TQ; qi++) {
        float en = fmaf(-2.0f, e2[qi], vbSum);
        if (mok == 0) en = -1e10f;
        p[qi] = __expf(en);
        float s = p[qi];
        #pragma unroll
        for (int off = 32; off > 0; off >>= 1) s += __shfl_xor(s, off, 64);
        if ((t & 63) == 0) rsum[qi][wave] = s;
    }
    __syncthreads();
    #pragma unroll
    for (int qi = 0; qi < TQ; qi++) {
        float gs = rsum[qi][0] + rsum[qi][1] + rsum[qi][2] +
                   rsum[qi][3] + rsum[qi][4] + rsum[qi][5];
        p[qi] *= 1.0f / gs;
        ps[qi][t] = p[qi];
        size_t aidx = XELEMS + (size_t)(bh * LSEQ + q0 + qi) * LSEQ + t;
        if (f) ((float*)dout)[aidx] = p[qi];
        else   ((ushort_t*)dout)[aidx] = f2bf(p[qi]);
    }
    __syncthreads();

    const int dq = t & 15;
    const int ksub = t >> 4;
    const float* vb4 = Vh + (size_t)bh * LSEQ * 64 + dq * 4;
    float4 acc[TQ];
    #pragma unroll
    for (int qi = 0; qi < TQ; qi++) acc[qi] = make_float4(0.f, 0.f, 0.f, 0.f);
    for (int kk = ksub; kk < LSEQ; kk += 24) {
        float4 v4 = *reinterpret_cast<const float4*>(vb4 + (size_t)kk * 64);
        #pragma unroll
        for (int qi = 0; qi < TQ; qi++) {
            float pq = ps[qi][kk];
            acc[qi].x = fmaf(pq, v4.x, acc[qi].x);
            acc[qi].y = fmaf(pq, v4.y, acc[qi].y);
            acc[qi].z = fmaf(pq, v4.z, acc[qi].z);
            acc[qi].w = fmaf(pq, v4.w, acc[qi].w);
        }
    }
    #pragma unroll
    for (int qi = 0; qi < TQ; qi++) {
        #pragma unroll
        for (int off = 16; off <= 32; off <<= 1) {
            acc[qi].x += __shfl_xor(acc[qi].x, off, 64);
            acc[qi].y += __shfl_xor(acc[qi].y, off, 64);
            acc[qi].z += __shfl_xor(acc[qi].z, off, 64);
            acc[qi].w += __shfl_xor(acc[qi].w, off, 64);
        }
    }
    if ((t & 63) < 16) {
        #pragma unroll
        for (int qi = 0; qi < TQ; qi++) {
            red[wave][qi][dq][0] = acc[qi].x;
            red[wave][qi][dq][1] = acc[qi].y;
            red[wave][qi][dq][2] = acc[qi].z;
            red[wave][qi][dq][3] = acc[qi].w;
        }
    }
    __syncthreads();
    if (t < 256) {
        int d = t & 63;
        #pragma unroll
        for (int half = 0; half < 2; half++) {
            int qi = (t >> 6) + half * 4;
            float sx = 0.f;
            #pragma unroll
            for (int w = 0; w < 6; w++) sx += red[w][qi][d >> 2][d & 3];
            Xh[((size_t)(b * LSEQ + q0 + qi) * NH + h) * 64 + d] = sx;
        }
    }
}

// ---------------------------------------------------------------------------
// Kernel 3: output projection via bf16 MFMA. x = Xh @ Wo^T + bo, dual-dtype.
// r15: same in-block split-K x2 as gemm_qkv (192 blocks x 2 waves was
// 0.375 waves/SIMD — fully exposed latency chain; now 4 waves, 4 K-iters).
// ---------------------------------------------------------------------------
__global__ __launch_bounds__(256) void gemm_out(
    const void* qp, const void* Wop, const void* bop,
    const float* __restrict__ ws_in, void* __restrict__ dout)
{
    __shared__ int s_cnt;
    __shared__ ushort_t smA[2][32 * LDSTR];
    __shared__ ushort_t smB[2][64 * LDSTR];
    __shared__ float sred[32][65];
    __shared__ float biasF[64];
    const int f = block_detect((const unsigned int*)qp, &s_cnt);

    const float* Xh = ws_in + OFF_XH;
    const int col0 = blockIdx.x * 64;
    const int row0 = blockIdx.y * 32;
    const int t = threadIdx.x;
    const int th = t & 127;
    const int kh = t >> 7;
    const int w2 = (t >> 6) & 1;
    const int l16 = t & 15, quad = (t & 63) >> 4;

    if (t < 64) biasF[t] = ld1(bop, col0 + t, f);

    const int arow = th >> 2, acol = (th & 3) * 16;
    const int brow = th >> 1, bcol = (th & 1) * 32;
    const float* Ab = Xh + (size_t)(row0 + arow) * 512 + kh * 256 + acol;
    const size_t bbase = (size_t)(col0 + brow) * 512 + kh * 256 + bcol;

    float4 a4[4], b4[8];
    #pragma unroll
    for (int i = 0; i < 4; i++) a4[i] = *reinterpret_cast<const float4*>(Ab + i * 4);
    #pragma unroll
    for (int i = 0; i < 8; i++) b4[i] = ld4(Wop, bbase + i * 4, f);

    f32x4 acc[4];
    #pragma unroll
    for (int nt = 0; nt < 4; nt++) acc[nt] = (f32x4){0.f, 0.f, 0.f, 0.f};

    for (int k0 = 0; k0 < 256; k0 += 64) {
        __syncthreads();
        *reinterpret_cast<uint4*>(&smA[kh][arow * LDSTR + acol])     = packu4(a4[0], a4[1]);
        *reinterpret_cast<uint4*>(&smA[kh][arow * LDSTR + acol + 8]) = packu4(a4[2], a4[3]);
        *reinterpret_cast<uint4*>(&smB[kh][brow * LDSTR + bcol])      = packu4(b4[0], b4[1]);
        *reinterpret_cast<uint4*>(&smB[kh][brow * LDSTR + bcol + 8])  = packu4(b4[2], b4[3]);
        *reinterpret_cast<uint4*>(&smB[kh][brow * LDSTR + bcol + 16]) = packu4(b4[4], b4[5]);
        *reinterpret_cast<uint4*>(&smB[kh][brow * LDSTR + bcol + 24]) = packu4(b4[6], b4[7]);
        __syncthreads();
        if (k0 + 64 < 256) {
            #pragma unroll
            for (int i = 0; i < 4; i++)
                a4[i] = *reinterpret_cast<const float4*>(Ab + k0 + 64 + i * 4);
            #pragma unroll
            for (int i = 0; i < 8; i++) b4[i] = ld4(Wop, bbase + k0 + 64 + i * 4, f);
        }
        #pragma unroll
        for (int kk = 0; kk < 2; kk++) {
            bf16x8 af = *reinterpret_cast<const bf16x8*>(
                &smA[kh][(w2 * 16 + l16) * LDSTR + kk * 32 + quad * 8]);
            #pragma unroll
            for (int nt = 0; nt < 4; nt++) {
                bf16x8 bfr = *reinterpret_cast<const bf16x8*>(
                    &smB[kh][(nt * 16 + l16) * LDSTR + kk * 32 + quad * 8]);
                acc[nt] = __builtin_amdgcn_mfma_f32_16x16x32_bf16(af, bfr, acc[nt], 0, 0, 0);
            }
        }
    }

    if (kh == 1) {
        #pragma unroll
        for (int nt = 0; nt < 4; nt++)
            #pragma unroll
            for (int r = 0; r < 4; r++)
                sred[w2 * 16 + quad * 4 + r][nt * 16 + l16] = acc[nt][r];
    }
    __syncthreads();
    if (kh == 0) {
        #pragma unroll
        for (int nt = 0; nt < 4; nt++) {
            int n = col0 + l16 + nt * 16;
            float bi = biasF[l16 + nt * 16];
            #pragma unroll
            for (int r = 0; r < 4; r++) {
                int m = row0 + w2 * 16 + quad * 4 + r;
                float c = acc[nt][r] + sred[w2 * 16 + quad * 4 + r][nt * 16 + l16] + bi;
                size_t idx = (size_t)m * 512 + n;
                if (f) ((float*)dout)[idx] = c;
                else   ((ushort_t*)dout)[idx] = f2bf(c);
            }
        }
    }
}

// ---------------------------------------------------------------------------
extern "C" void kernel_launch(void* const* d_in, const int* in_sizes, int n_in,
                              void* d_out, int out_size, void* d_ws, size_t ws_size,
                              hipStream_t stream)
{
    const void* qp = d_in[0];
    const void* kp = d_in[1];
    const void* vp = d_in[2];
    const int* mask = (const int*)d_in[3];
    const void* Wqp = d_in[4];  const void* bqp = d_in[5];
    const void* Wkp = d_in[6];  const void* bkp = d_in[7];
    const void* Wvp = d_in[8];  const void* bvp = d_in[9];
    const void* Wop = d_in[10]; const void* bop = d_in[11];
    const void* W1p = d_in[12]; const void* b1p = d_in[13];
    const void* W2p = d_in[14]; const void* b2p = d_in[15];
    const void* vwp = d_in[16]; const void* vbp = d_in[17];

    float* ws = (float*)d_ws;

    gemm_qkv<<<dim3(8, 24, 3), 256, 0, stream>>>(qp, kp, vp, Wqp, Wkp, Wvp,
                                                 W1p, W2p, bqp, bkp, b1p, b2p,
                                                 bvp, ws);
    attn_kernel<<<BH * QTILES, 384, 0, stream>>>(qp, vwp, vbp, ws, ws, mask, d_out);
    gemm_out<<<dim3(8, 24, 1), 256, 0, stream>>>(qp, Wop, bop, ws, d_out);
}

// Round 3
// 159.244 us; speedup vs baseline: 1.0154x; 1.0154x over previous
//
#include <hip/hip_runtime.h>

// Problem constants
#define BATCH 2
#define LSEQ 384
#define NHID 512
#define NH 8
#define DH 64
#define BH (BATCH*NH)          // 16
#define XELEMS ((size_t)768 * NHID)        // 393216 (x output elems)
#define TQ 8                   // q-rows per attn block
#define QTILES (LSEQ/TQ)       // 48

typedef unsigned short ushort_t;
typedef __attribute__((ext_vector_type(8))) short bf16x8;
typedef __attribute__((ext_vector_type(4))) float f32x4;
typedef __attribute__((ext_vector_type(2))) float f32x2;

__device__ __forceinline__ float bf2f(ushort_t u) {
    unsigned int v = ((unsigned int)u) << 16;
    return __uint_as_float(v);
}
__device__ __forceinline__ ushort_t f2bf(float f) {
    unsigned int u = __float_as_uint(f);
    unsigned int lsb = (u >> 16) & 1u;
    u += 0x7fffu + lsb;           // round-to-nearest-even
    return (ushort_t)(u >> 16);
}
// RNE bf16 pair-pack: 2x add + v_perm (ushort0=bf16(a), ushort1=bf16(b))
__device__ __forceinline__ unsigned pk_bf16(float a, float b) {
    unsigned ua = __float_as_uint(a), ub = __float_as_uint(b);
    ua += 0x7fffu + ((ua >> 16) & 1u);
    ub += 0x7fffu + ((ub >> 16) & 1u);
    return __builtin_amdgcn_perm(ub, ua, 0x07060302);
}
__device__ __forceinline__ float ld1(const void* p, size_t i, int f) {
    return f ? ((const float*)p)[i] : bf2f(((const ushort_t*)p)[i]);
}
__device__ __forceinline__ float4 ld4(const void* p, size_t i, int f) {
    if (f) return ((const float4*)p)[i >> 2];
    ushort4 u = ((const ushort4*)p)[i >> 2];
    return make_float4(bf2f(u.x), bf2f(u.y), bf2f(u.z), bf2f(u.w));
}
__device__ __forceinline__ int block_detect(const unsigned int* q, int* cnt) {
    int t = threadIdx.x;
    if (t == 0) *cnt = 0;
    __syncthreads();
    int n = blockDim.x < 256 ? blockDim.x : 256;
    if (t < n) {
        unsigned int elo = (q[t] >> 7) & 0xFFu;
        if (elo >= 100u && elo <= 150u) atomicAdd(cnt, 1);
    }
    __syncthreads();
    return (*cnt * 2 > n) ? 0 : 1;     // 0 = bf16-packed, 1 = fp32
}
__device__ __forceinline__ uint4 packu4(float4 a, float4 b) {
    uint4 r;
    r.x = pk_bf16(a.x, a.y); r.y = pk_bf16(a.z, a.w);
    r.z = pk_bf16(b.x, b.y); r.w = pk_bf16(b.z, b.w);
    return r;
}
__device__ __forceinline__ bf16x8 pack_bf8(float4 a, float4 b) {
    union { uint4 u; bf16x8 v; } r;
    r.u = packu4(a, b);
    return r.v;
}

// ---------------- workspace layout (float offsets) ----------------
#define OFF_ETQ   16                  // Etq = exp(2 tq)  [bh][l][d]
#define OFF_ETK   (16 + 393216)       // Etk = exp(2 tk)  [bh][l][d] (row-major)
#define OFF_VH    (16 + 2*393216)     // V                [bh][l][d]
#define OFF_XH    (16 + 3*393216)     // context [B,L,H,D]

#define LDSTR 72   // LDS row stride in ushorts (144 B)

// ---------------------------------------------------------------------------
// Kernel 1: QKV projection via bf16 MFMA. 32(m) x 64(n=head) tile, 128 thr
// (2 waves), K=512 step 64, reg prefetch. Modes 0/1 fold W1/W2 via a second
// in-register MFMA pass and write Etq/Etk = exp(2(..+biasF)) row-major;
// mode 2 writes V + bv.
// r16 NOTE: r15's in-block split-K x2 (256 thr, K-loop 4 iters) REGRESSED
// +2.5us — these kernels are only ~2-4us each; the extra syncs + LDS
// cross-half reduce cost more than the latency saved. Keep 128-thr form.
// ---------------------------------------------------------------------------
__global__ __launch_bounds__(128) void gemm_qkv(
    const void* qp, const void* kp, const void* vp,
    const void* Wqp, const void* Wkp, const void* Wvp,
    const void* W1p, const void* W2p,
    const void* bqp, const void* bkp, const void* b1p, const void* b2p,
    const void* bvp, float* __restrict__ ws)
{
    __shared__ int s_cnt;
    __shared__ ushort_t smA[32 * LDSTR];
    __shared__ ushort_t smB[64 * LDSTR];
    __shared__ float biasF[64];
    const int f = block_detect((const unsigned int*)qp, &s_cnt);

    const int mode = blockIdx.z;
    const void* A = (mode == 0) ? qp : (mode == 1) ? kp : vp;
    const void* W = (mode == 0) ? Wqp : (mode == 1) ? Wkp : Wvp;
    const void* W1x = (mode == 1) ? W2p : W1p;

    const int h    = blockIdx.x;
    const int col0 = h * 64;
    const int row0 = blockIdx.y * 32;
    const int t = threadIdx.x;
    const int w = t >> 6, l16 = t & 15, quad = (t & 63) >> 4;

    // fused bias into LDS (threads 0..63), overlapped with prefetch
    if (t < 64) {
        if (mode == 2) {
            biasF[t] = ld1(bvp, col0 + t, f);
        } else {
            const void* b1x = (mode == 1) ? b2p : b1p;
            const void* bx  = (mode == 1) ? bkp : bqp;
            float s = ld1(b1x, t, f);
            for (int j = 0; j < 64; j++)
                s = fmaf(ld1(W1x, (size_t)t * 64 + j, f), ld1(bx, h * 64 + j, f), s);
            biasF[t] = s;
        }
    }

    const int arow = t >> 2, acol = (t & 3) * 16;
    const int brow = t >> 1, bcol = (t & 1) * 32;
    const size_t abase = (size_t)(row0 + arow) * 512 + acol;
    const size_t bbase = (size_t)(col0 + brow) * 512 + bcol;

    float4 a4[4], b4[8];
    #pragma unroll
    for (int i = 0; i < 4; i++) a4[i] = ld4(A, abase + i * 4, f);
    #pragma unroll
    for (int i = 0; i < 8; i++) b4[i] = ld4(W, bbase + i * 4, f);

    f32x4 acc[4];
    #pragma unroll
    for (int nt = 0; nt < 4; nt++) acc[nt] = (f32x4){0.f, 0.f, 0.f, 0.f};

    for (int k0 = 0; k0 < 512; k0 += 64) {
        __syncthreads();
        *reinterpret_cast<uint4*>(&smA[arow * LDSTR + acol])     = packu4(a4[0], a4[1]);
        *reinterpret_cast<uint4*>(&smA[arow * LDSTR + acol + 8]) = packu4(a4[2], a4[3]);
        *reinterpret_cast<uint4*>(&smB[brow * LDSTR + bcol])      = packu4(b4[0], b4[1]);
        *reinterpret_cast<uint4*>(&smB[brow * LDSTR + bcol + 8])  = packu4(b4[2], b4[3]);
        *reinterpret_cast<uint4*>(&smB[brow * LDSTR + bcol + 16]) = packu4(b4[4], b4[5]);
        *reinterpret_cast<uint4*>(&smB[brow * LDSTR + bcol + 24]) = packu4(b4[6], b4[7]);
        __syncthreads();
        if (k0 + 64 < 512) {
            #pragma unroll
            for (int i = 0; i < 4; i++) a4[i] = ld4(A, abase + k0 + 64 + i * 4, f);
            #pragma unroll
            for (int i = 0; i < 8; i++) b4[i] = ld4(W, bbase + k0 + 64 + i * 4, f);
        }
        #pragma unroll
        for (int kk = 0; kk < 2; kk++) {
            bf16x8 af = *reinterpret_cast<const bf16x8*>(
                &smA[(w * 16 + l16) * LDSTR + kk * 32 + quad * 8]);
            #pragma unroll
            for (int nt = 0; nt < 4; nt++) {
                bf16x8 bfr = *reinterpret_cast<const bf16x8*>(
                    &smB[(nt * 16 + l16) * LDSTR + kk * 32 + quad * 8]);
                acc[nt] = __builtin_amdgcn_mfma_f32_16x16x32_bf16(af, bfr, acc[nt], 0, 0, 0);
            }
        }
    }

    const int b  = (row0 >= LSEQ) ? 1 : 0;
    const int lbase = row0 - b * LSEQ + w * 16;
    const int bh = b * NH + h;

    if (mode == 2) {
        float* Out = ws + OFF_VH;
        #pragma unroll
        for (int nt = 0; nt < 4; nt++) {
            int d = l16 + nt * 16;
            float bi = biasF[d];
            #pragma unroll
            for (int r = 0; r < 4; r++) {
                int l = lbase + quad * 4 + r;
                Out[(size_t)(bh * LSEQ + l) * 64 + d] = acc[nt][r] + bi;
            }
        }
    } else {
        // ---- fold: restage acc (bf16) in wave-private LDS rows, x W1^T ----
        #pragma unroll
        for (int nt = 0; nt < 4; nt++)
            #pragma unroll
            for (int r = 0; r < 4; r++)
                smA[(w * 16 + quad * 4 + r) * LDSTR + l16 + nt * 16] =
                    f2bf(acc[nt][r]);
        f32x4 acc2[4];
        #pragma unroll
        for (int nt = 0; nt < 4; nt++) acc2[nt] = (f32x4){0.f, 0.f, 0.f, 0.f};
        #pragma unroll
        for (int kk = 0; kk < 2; kk++) {
            bf16x8 af2 = *reinterpret_cast<const bf16x8*>(
                &smA[(w * 16 + l16) * LDSTR + kk * 32 + quad * 8]);
            #pragma unroll
            for (int nt = 0; nt < 4; nt++) {
                int od = nt * 16 + l16, j0 = kk * 32 + quad * 8;
                float4 wa = ld4(W1x, (size_t)od * 64 + j0, f);
                float4 wb = ld4(W1x, (size_t)od * 64 + j0 + 4, f);
                bf16x8 bfw = pack_bf8(wa, wb);
                acc2[nt] = __builtin_amdgcn_mfma_f32_16x16x32_bf16(af2, bfw, acc2[nt], 0, 0, 0);
            }
        }
        float* Out = ws + ((mode == 0) ? OFF_ETQ : OFF_ETK);   // both row-major
        #pragma unroll
        for (int nt = 0; nt < 4; nt++) {
            int d = l16 + nt * 16;
            float bi = biasF[d];
            #pragma unroll
            for (int r = 0; r < 4; r++) {
                int l = lbase + quad * 4 + r;
                Out[(size_t)(bh * LSEQ + l) * 64 + d] =
                    __expf(2.f * (acc2[nt][r] + bi));
            }
        }
    }
}

// ---------------------------------------------------------------------------
// Kernel 2: additive attention, TQ=8, 384 threads (t = k). Etk row-major:
// thread t reads its Etk row via 16 b128 loads (deep MLP, L1 reuse).
// Energy (r16): 4-WAY reciprocal grouping + packed fp32 (v_pk_* VOP3P).
//   1/u1+1/u2+1/u3+1/u4 = [(u1+u2)u3u4 + (u3+u4)u1u2] * rcp(u1u2u3u4)
// with u_d = fma(Etq/w_d, Ek, 1/w_d) = (x_d+1)/w_d. Vectorized over q-pairs
// as float2 via __builtin_elementwise_fma -> v_pk_fma_f32 (gfx90a+).
// Per thread: ~832 VALU instr (1664 cyc) + 128 rcp (1024 trans cyc)
// vs r14's 1280 VALU (2560) + 256 rcp (2048). q-operands loaded as uniform
// f32x2 LDS reads per step to keep VGPR under the (384,6) cap (~85).
// NOTE (r13 post-mortem): do NOT add per-thread arrays to the energy loop —
// under __launch_bounds__(384,6) they spill to scratch (372 MB FETCH, 3x dur).
// ---------------------------------------------------------------------------
__global__ __launch_bounds__(384, 6) void attn_kernel(
    const void* qp, const void* vwp, const void* vbp,
    const float* __restrict__ ws_in, float* __restrict__ ws,
    const int* __restrict__ mask, void* __restrict__ dout)
{
    __shared__ int s_cnt;
    const int f = block_detect((const unsigned int*)qp, &s_cnt);

    const float* Etq = ws_in + OFF_ETQ;
    const float* Etk = ws_in + OFF_ETK;
    const float* Vh  = ws_in + OFF_VH;
    float* Xh = ws + OFF_XH;

    const int bid = blockIdx.x;
    const int qt = bid % QTILES;
    const int bh = bid / QTILES;
    const int q0 = qt * TQ;
    const int b  = bh >> 3;
    const int h  = bh & 7;
    const int t  = threadIdx.x;
    const int wave = t >> 6;

    __shared__ __align__(16) float etq8[64][TQ];   // Etq / w_d
    __shared__ f32x2 cws2[64];                      // splat(1 / w_d)
    __shared__ float ps[TQ][LSEQ];
    __shared__ float red[6][TQ][16][4];
    __shared__ float rsum[TQ][6];
    __shared__ float s_vb;

    for (int i = t; i < TQ * 64; i += 384) {
        int qi = i >> 6, d = i & 63;
        float wv = ld1(vwp, d, f);
        etq8[d][qi] = Etq[(size_t)(bh * LSEQ + q0 + qi) * 64 + d] / wv;
    }
    if (t < 64) {
        float v = ld1(vwp, t, f);
        float r = 1.0f / v;
        cws2[t] = (f32x2){r, r};
        #pragma unroll
        for (int off = 32; off > 0; off >>= 1) v += __shfl_xor(v, off, 64);
        if (t == 0) s_vb = ld1(vbp, 0, f) + v;
    }
    const int mok = mask[b * LSEQ + t];
    __syncthreads();
    const float vbSum = s_vb;

    f32x2 e2p0 = {0.f, 0.f}, e2p1 = {0.f, 0.f};
    f32x2 e2p2 = {0.f, 0.f}, e2p3 = {0.f, 0.f};
    const float* ekrow = Etk + (size_t)(bh * LSEQ + t) * 64;
    #pragma unroll 2
    for (int dv = 0; dv < 16; dv++) {
        float4 ek4 = *reinterpret_cast<const float4*>(ekrow + dv * 4);
        const int d0 = dv * 4;
        const f32x2 vcA = cws2[d0];
        const f32x2 vcB = cws2[d0 + 1];
        const f32x2 vcC = cws2[d0 + 2];
        const f32x2 vcD = cws2[d0 + 3];
        const f32x2 ekA = {ek4.x, ek4.x};
        const f32x2 ekB = {ek4.y, ek4.y};
        const f32x2 ekC = {ek4.z, ek4.z};
        const f32x2 ekD = {ek4.w, ek4.w};
#define ESTEP(EP, i) { \
        f32x2 ua = __builtin_elementwise_fma( \
            *reinterpret_cast<const f32x2*>(&etq8[d0][2*(i)]),     ekA, vcA); \
        f32x2 ub = __builtin_elementwise_fma( \
            *reinterpret_cast<const f32x2*>(&etq8[d0 + 1][2*(i)]), ekB, vcB); \
        f32x2 uc = __builtin_elementwise_fma( \
            *reinterpret_cast<const f32x2*>(&etq8[d0 + 2][2*(i)]), ekC, vcC); \
        f32x2 ud = __builtin_elementwise_fma( \
            *reinterpret_cast<const f32x2*>(&etq8[d0 + 3][2*(i)]), ekD, vcD); \
        f32x2 pab = ua * ub, pcd = uc * ud; \
        f32x2 P = pab * pcd; \
        f32x2 num = __builtin_elementwise_fma(ua + ub, pcd, (uc + ud) * pab); \
        f32x2 rP; \
        rP.x = __builtin_amdgcn_rcpf(P.x); \
        rP.y = __builtin_amdgcn_rcpf(P.y); \
        EP = __builtin_elementwise_fma(num, rP, EP); }
        ESTEP(e2p0, 0)
        ESTEP(e2p1, 1)
        ESTEP(e2p2, 2)
        ESTEP(e2p3, 3)
#undef ESTEP
    }
    const float ex[TQ] = {e2p0.x, e2p0.y, e2p1.x, e2p1.y,
                          e2p2.x, e2p2.y, e2p3.x, e2p3.y};

    float p[TQ];
    #pragma unroll
    for (int qi = 0; qi < TQ; qi++) {
        float en = fmaf(-2.0f, ex[qi], vbSum);
        if (mok == 0) en = -1e10f;
        p[qi] = __expf(en);
        float s = p[qi];
        #pragma unroll
        for (int off = 32; off > 0; off >>= 1) s += __shfl_xor(s, off, 64);
        if ((t & 63) == 0) rsum[qi][wave] = s;
    }
    __syncthreads();
    #pragma unroll
    for (int qi = 0; qi < TQ; qi++) {
        float gs = rsum[qi][0] + rsum[qi][1] + rsum[qi][2] +
                   rsum[qi][3] + rsum[qi][4] + rsum[qi][5];
        p[qi] *= 1.0f / gs;
        ps[qi][t] = p[qi];
        size_t aidx = XELEMS + (size_t)(bh * LSEQ + q0 + qi) * LSEQ + t;
        if (f) ((float*)dout)[aidx] = p[qi];
        else   ((ushort_t*)dout)[aidx] = f2bf(p[qi]);
    }
    __syncthreads();

    const int dq = t & 15;
    const int ksub = t >> 4;
    const float* vb4 = Vh + (size_t)bh * LSEQ * 64 + dq * 4;
    float4 acc[TQ];
    #pragma unroll
    for (int qi = 0; qi < TQ; qi++) acc[qi] = make_float4(0.f, 0.f, 0.f, 0.f);
    for (int kk = ksub; kk < LSEQ; kk += 24) {
        float4 v4 = *reinterpret_cast<const float4*>(vb4 + (size_t)kk * 64);
        #pragma unroll
        for (int qi = 0; qi < TQ; qi++) {
            float pq = ps[qi][kk];
            acc[qi].x = fmaf(pq, v4.x, acc[qi].x);
            acc[qi].y = fmaf(pq, v4.y, acc[qi].y);
            acc[qi].z = fmaf(pq, v4.z, acc[qi].z);
            acc[qi].w = fmaf(pq, v4.w, acc[qi].w);
        }
    }
    #pragma unroll
    for (int qi = 0; qi < TQ; qi++) {
        #pragma unroll
        for (int off = 16; off <= 32; off <<= 1) {
            acc[qi].x += __shfl_xor(acc[qi].x, off, 64);
            acc[qi].y += __shfl_xor(acc[qi].y, off, 64);
            acc[qi].z += __shfl_xor(acc[qi].z, off, 64);
            acc[qi].w += __shfl_xor(acc[qi].w, off, 64);
        }
    }
    if ((t & 63) < 16) {
        #pragma unroll
        for (int qi = 0; qi < TQ; qi++) {
            red[wave][qi][dq][0] = acc[qi].x;
            red[wave][qi][dq][1] = acc[qi].y;
            red[wave][qi][dq][2] = acc[qi].z;
            red[wave][qi][dq][3] = acc[qi].w;
        }
    }
    __syncthreads();
    if (t < 256) {
        int d = t & 63;
        #pragma unroll
        for (int half = 0; half < 2; half++) {
            int qi = (t >> 6) + half * 4;
            float sx = 0.f;
            #pragma unroll
            for (int w = 0; w < 6; w++) sx += red[w][qi][d >> 2][d & 3];
            Xh[((size_t)(b * LSEQ + q0 + qi) * NH + h) * 64 + d] = sx;
        }
    }
}

// ---------------------------------------------------------------------------
// Kernel 3: output projection via bf16 MFMA. x = Xh @ Wo^T + bo, dual-dtype.
// (r16: reverted r15 split-K — see gemm_qkv note.)
// ---------------------------------------------------------------------------
__global__ __launch_bounds__(128) void gemm_out(
    const void* qp, const void* Wop, const void* bop,
    const float* __restrict__ ws_in, void* __restrict__ dout)
{
    __shared__ int s_cnt;
    __shared__ ushort_t smA[32 * LDSTR];
    __shared__ ushort_t smB[64 * LDSTR];
    __shared__ float biasF[64];
    const int f = block_detect((const unsigned int*)qp, &s_cnt);

    const float* Xh = ws_in + OFF_XH;
    const int col0 = blockIdx.x * 64;
    const int row0 = blockIdx.y * 32;
    const int t = threadIdx.x;
    const int w = t >> 6, l16 = t & 15, quad = (t & 63) >> 4;

    if (t < 64) biasF[t] = ld1(bop, col0 + t, f);

    const int arow = t >> 2, acol = (t & 3) * 16;
    const int brow = t >> 1, bcol = (t & 1) * 32;
    const float* Ab = Xh + (size_t)(row0 + arow) * 512 + acol;
    const size_t bbase = (size_t)(col0 + brow) * 512 + bcol;

    float4 a4[4], b4[8];
    #pragma unroll
    for (int i = 0; i < 4; i++) a4[i] = *reinterpret_cast<const float4*>(Ab + i * 4);
    #pragma unroll
    for (int i = 0; i < 8; i++) b4[i] = ld4(Wop, bbase + i * 4, f);

    f32x4 acc[4];
    #pragma unroll
    for (int nt = 0; nt < 4; nt++) acc[nt] = (f32x4){0.f, 0.f, 0.f, 0.f};

    for (int k0 = 0; k0 < 512; k0 += 64) {
        __syncthreads();
        *reinterpret_cast<uint4*>(&smA[arow * LDSTR + acol])     = packu4(a4[0], a4[1]);
        *reinterpret_cast<uint4*>(&smA[arow * LDSTR + acol + 8]) = packu4(a4[2], a4[3]);
        *reinterpret_cast<uint4*>(&smB[brow * LDSTR + bcol])      = packu4(b4[0], b4[1]);
        *reinterpret_cast<uint4*>(&smB[brow * LDSTR + bcol + 8])  = packu4(b4[2], b4[3]);
        *reinterpret_cast<uint4*>(&smB[brow * LDSTR + bcol + 16]) = packu4(b4[4], b4[5]);
        *reinterpret_cast<uint4*>(&smB[brow * LDSTR + bcol + 24]) = packu4(b4[6], b4[7]);
        __syncthreads();
        if (k0 + 64 < 512) {
            #pragma unroll
            for (int i = 0; i < 4; i++)
                a4[i] = *reinterpret_cast<const float4*>(Ab + k0 + 64 + i * 4);
            #pragma unroll
            for (int i = 0; i < 8; i++) b4[i] = ld4(Wop, bbase + k0 + 64 + i * 4, f);
        }
        #pragma unroll
        for (int kk = 0; kk < 2; kk++) {
            bf16x8 af = *reinterpret_cast<const bf16x8*>(
                &smA[(w * 16 + l16) * LDSTR + kk * 32 + quad * 8]);
            #pragma unroll
            for (int nt = 0; nt < 4; nt++) {
                bf16x8 bfr = *reinterpret_cast<const bf16x8*>(
                    &smB[(nt * 16 + l16) * LDSTR + kk * 32 + quad * 8]);
                acc[nt] = __builtin_amdgcn_mfma_f32_16x16x32_bf16(af, bfr, acc[nt], 0, 0, 0);
            }
        }
    }

    #pragma unroll
    for (int nt = 0; nt < 4; nt++) {
        int n = col0 + l16 + nt * 16;
        float bi = biasF[l16 + nt * 16];
        #pragma unroll
        for (int r = 0; r < 4; r++) {
            int m = row0 + w * 16 + quad * 4 + r;
            float c = acc[nt][r] + bi;
            size_t idx = (size_t)m * 512 + n;
            if (f) ((float*)dout)[idx] = c;
            else   ((ushort_t*)dout)[idx] = f2bf(c);
        }
    }
}

// ---------------------------------------------------------------------------
extern "C" void kernel_launch(void* const* d_in, const int* in_sizes, int n_in,
                              void* d_out, int out_size, void* d_ws, size_t ws_size,
                              hipStream_t stream)
{
    const void* qp = d_in[0];
    const void* kp = d_in[1];
    const void* vp = d_in[2];
    const int* mask = (const int*)d_in[3];
    const void* Wqp = d_in[4];  const void* bqp = d_in[5];
    const void* Wkp = d_in[6];  const void* bkp = d_in[7];
    const void* Wvp = d_in[8];  const void* bvp = d_in[9];
    const void* Wop = d_in[10]; const void* bop = d_in[11];
    const void* W1p = d_in[12]; const void* b1p = d_in[13];
    const void* W2p = d_in[14]; const void* b2p = d_in[15];
    const void* vwp = d_in[16]; const void* vbp = d_in[17];

    float* ws = (float*)d_ws;

    gemm_qkv<<<dim3(8, 24, 3), 128, 0, stream>>>(qp, kp, vp, Wqp, Wkp, Wvp,
                                                 W1p, W2p, bqp, bkp, b1p, b2p,
                                                 bvp, ws);
    attn_kernel<<<BH * QTILES, 384, 0, stream>>>(qp, vwp, vbp, ws, ws, mask, d_out);
    gemm_out<<<dim3(8, 24, 1), 128, 0, stream>>>(qp, Wop, bop, ws, d_out);
}

// Round 5
// 159.101 us; speedup vs baseline: 1.0163x; 1.0009x over previous
//
#include <hip/hip_runtime.h>

// Problem constants
#define BATCH 2
#define LSEQ 384
#define NHID 512
#define NH 8
#define DH 64
#define BH (BATCH*NH)          // 16
#define XELEMS ((size_t)768 * NHID)        // 393216 (x output elems)
#define TQ 8                   // q-rows per attn block
#define QTILES (LSEQ/TQ)       // 48

typedef unsigned short ushort_t;
typedef __attribute__((ext_vector_type(8))) short bf16x8;
typedef __attribute__((ext_vector_type(4))) float f32x4;

__device__ __forceinline__ float bf2f(ushort_t u) {
    unsigned int v = ((unsigned int)u) << 16;
    return __uint_as_float(v);
}
__device__ __forceinline__ ushort_t f2bf(float f) {
    unsigned int u = __float_as_uint(f);
    unsigned int lsb = (u >> 16) & 1u;
    u += 0x7fffu + lsb;           // round-to-nearest-even
    return (ushort_t)(u >> 16);
}
// RNE bf16 pair-pack: 2x add + v_perm (ushort0=bf16(a), ushort1=bf16(b))
__device__ __forceinline__ unsigned pk_bf16(float a, float b) {
    unsigned ua = __float_as_uint(a), ub = __float_as_uint(b);
    ua += 0x7fffu + ((ua >> 16) & 1u);
    ub += 0x7fffu + ((ub >> 16) & 1u);
    return __builtin_amdgcn_perm(ub, ua, 0x07060302);
}
__device__ __forceinline__ float ld1(const void* p, size_t i, int f) {
    return f ? ((const float*)p)[i] : bf2f(((const ushort_t*)p)[i]);
}
__device__ __forceinline__ float4 ld4(const void* p, size_t i, int f) {
    if (f) return ((const float4*)p)[i >> 2];
    ushort4 u = ((const ushort4*)p)[i >> 2];
    return make_float4(bf2f(u.x), bf2f(u.y), bf2f(u.z), bf2f(u.w));
}
__device__ __forceinline__ int block_detect(const unsigned int* q, int* cnt) {
    int t = threadIdx.x;
    if (t == 0) *cnt = 0;
    __syncthreads();
    int n = blockDim.x < 256 ? blockDim.x : 256;
    if (t < n) {
        unsigned int elo = (q[t] >> 7) & 0xFFu;
        if (elo >= 100u && elo <= 150u) atomicAdd(cnt, 1);
    }
    __syncthreads();
    return (*cnt * 2 > n) ? 0 : 1;     // 0 = bf16-packed, 1 = fp32
}
__device__ __forceinline__ uint4 packu4(float4 a, float4 b) {
    uint4 r;
    r.x = pk_bf16(a.x, a.y); r.y = pk_bf16(a.z, a.w);
    r.z = pk_bf16(b.x, b.y); r.w = pk_bf16(b.z, b.w);
    return r;
}
__device__ __forceinline__ bf16x8 pack_bf8(float4 a, float4 b) {
    union { uint4 u; bf16x8 v; } r;
    r.u = packu4(a, b);
    return r.v;
}

// ---------------- workspace layout (float offsets) ----------------
#define OFF_ETQ   16                  // Etq = exp(2 tq)  [bh][l][d]
#define OFF_ETK   (16 + 393216)       // Etk = exp(2 tk)  [bh][l][d] (row-major)
#define OFF_VH    (16 + 2*393216)     // V                [bh][l][d]
#define OFF_XH    (16 + 3*393216)     // context [B,L,H,D]

#define LDSTR 72   // LDS row stride in ushorts (144 B)

// ---------------------------------------------------------------------------
// Kernel 1: QKV projection via bf16 MFMA. 32(m) x 64(n=head) tile, 128 thr
// (2 waves), K=512 step 64, reg prefetch. Modes 0/1 fold W1/W2 via a second
// in-register MFMA pass and write Etq/Etk = exp(2(..+biasF)) row-major;
// mode 2 writes V + bv.
// r15 NOTE: in-block split-K x2 (256 thr) REGRESSED +2.5us — kernels are
// only ~2-4us; extra syncs + LDS reduce cost more than latency saved.
// r17 NOTE: inline-asm v_pk_* energy math FAILED numerics (absmax 3.7e-2) —
// VOP3P via asm is unverifiable here; do not retry without disasm.
// r18: bias fold vectorized (ld4 pairs, 16 iters) — was 64-iter serial
// chain of 128 scalar loads competing with the 2-wave MFMA loop.
// ---------------------------------------------------------------------------
__global__ __launch_bounds__(128) void gemm_qkv(
    const void* qp, const void* kp, const void* vp,
    const void* Wqp, const void* Wkp, const void* Wvp,
    const void* W1p, const void* W2p,
    const void* bqp, const void* bkp, const void* b1p, const void* b2p,
    const void* bvp, float* __restrict__ ws)
{
    __shared__ int s_cnt;
    __shared__ ushort_t smA[32 * LDSTR];
    __shared__ ushort_t smB[64 * LDSTR];
    __shared__ float biasF[64];
    const int f = block_detect((const unsigned int*)qp, &s_cnt);

    const int mode = blockIdx.z;
    const void* A = (mode == 0) ? qp : (mode == 1) ? kp : vp;
    const void* W = (mode == 0) ? Wqp : (mode == 1) ? Wkp : Wvp;
    const void* W1x = (mode == 1) ? W2p : W1p;

    const int h    = blockIdx.x;
    const int col0 = h * 64;
    const int row0 = blockIdx.y * 32;
    const int t = threadIdx.x;
    const int w = t >> 6, l16 = t & 15, quad = (t & 63) >> 4;

    // fused bias into LDS (threads 0..63), overlapped with prefetch
    if (t < 64) {
        if (mode == 2) {
            biasF[t] = ld1(bvp, col0 + t, f);
        } else {
            const void* b1x = (mode == 1) ? b2p : b1p;
            const void* bx  = (mode == 1) ? bkp : bqp;
            float s = ld1(b1x, t, f);
            for (int j = 0; j < 64; j += 4) {
                float4 wv = ld4(W1x, (size_t)t * 64 + j, f);
                float4 bv = ld4(bx, (size_t)h * 64 + j, f);
                s = fmaf(wv.x, bv.x, s);
                s = fmaf(wv.y, bv.y, s);
                s = fmaf(wv.z, bv.z, s);
                s = fmaf(wv.w, bv.w, s);
            }
            biasF[t] = s;
        }
    }

    const int arow = t >> 2, acol = (t & 3) * 16;
    const int brow = t >> 1, bcol = (t & 1) * 32;
    const size_t abase = (size_t)(row0 + arow) * 512 + acol;
    const size_t bbase = (size_t)(col0 + brow) * 512 + bcol;

    float4 a4[4], b4[8];
    #pragma unroll
    for (int i = 0; i < 4; i++) a4[i] = ld4(A, abase + i * 4, f);
    #pragma unroll
    for (int i = 0; i < 8; i++) b4[i] = ld4(W, bbase + i * 4, f);

    f32x4 acc[4];
    #pragma unroll
    for (int nt = 0; nt < 4; nt++) acc[nt] = (f32x4){0.f, 0.f, 0.f, 0.f};

    for (int k0 = 0; k0 < 512; k0 += 64) {
        __syncthreads();
        *reinterpret_cast<uint4*>(&smA[arow * LDSTR + acol])     = packu4(a4[0], a4[1]);
        *reinterpret_cast<uint4*>(&smA[arow * LDSTR + acol + 8]) = packu4(a4[2], a4[3]);
        *reinterpret_cast<uint4*>(&smB[brow * LDSTR + bcol])      = packu4(b4[0], b4[1]);
        *reinterpret_cast<uint4*>(&smB[brow * LDSTR + bcol + 8])  = packu4(b4[2], b4[3]);
        *reinterpret_cast<uint4*>(&smB[brow * LDSTR + bcol + 16]) = packu4(b4[4], b4[5]);
        *reinterpret_cast<uint4*>(&smB[brow * LDSTR + bcol + 24]) = packu4(b4[6], b4[7]);
        __syncthreads();
        if (k0 + 64 < 512) {
            #pragma unroll
            for (int i = 0; i < 4; i++) a4[i] = ld4(A, abase + k0 + 64 + i * 4, f);
            #pragma unroll
            for (int i = 0; i < 8; i++) b4[i] = ld4(W, bbase + k0 + 64 + i * 4, f);
        }
        #pragma unroll
        for (int kk = 0; kk < 2; kk++) {
            bf16x8 af = *reinterpret_cast<const bf16x8*>(
                &smA[(w * 16 + l16) * LDSTR + kk * 32 + quad * 8]);
            #pragma unroll
            for (int nt = 0; nt < 4; nt++) {
                bf16x8 bfr = *reinterpret_cast<const bf16x8*>(
                    &smB[(nt * 16 + l16) * LDSTR + kk * 32 + quad * 8]);
                acc[nt] = __builtin_amdgcn_mfma_f32_16x16x32_bf16(af, bfr, acc[nt], 0, 0, 0);
            }
        }
    }

    const int b  = (row0 >= LSEQ) ? 1 : 0;
    const int lbase = row0 - b * LSEQ + w * 16;
    const int bh = b * NH + h;

    if (mode == 2) {
        float* Out = ws + OFF_VH;
        #pragma unroll
        for (int nt = 0; nt < 4; nt++) {
            int d = l16 + nt * 16;
            float bi = biasF[d];
            #pragma unroll
            for (int r = 0; r < 4; r++) {
                int l = lbase + quad * 4 + r;
                Out[(size_t)(bh * LSEQ + l) * 64 + d] = acc[nt][r] + bi;
            }
        }
    } else {
        // ---- fold: restage acc (bf16) in wave-private LDS rows, x W1^T ----
        #pragma unroll
        for (int nt = 0; nt < 4; nt++)
            #pragma unroll
            for (int r = 0; r < 4; r++)
                smA[(w * 16 + quad * 4 + r) * LDSTR + l16 + nt * 16] =
                    f2bf(acc[nt][r]);
        f32x4 acc2[4];
        #pragma unroll
        for (int nt = 0; nt < 4; nt++) acc2[nt] = (f32x4){0.f, 0.f, 0.f, 0.f};
        #pragma unroll
        for (int kk = 0; kk < 2; kk++) {
            bf16x8 af2 = *reinterpret_cast<const bf16x8*>(
                &smA[(w * 16 + l16) * LDSTR + kk * 32 + quad * 8]);
            #pragma unroll
            for (int nt = 0; nt < 4; nt++) {
                int od = nt * 16 + l16, j0 = kk * 32 + quad * 8;
                float4 wa = ld4(W1x, (size_t)od * 64 + j0, f);
                float4 wb = ld4(W1x, (size_t)od * 64 + j0 + 4, f);
                bf16x8 bfw = pack_bf8(wa, wb);
                acc2[nt] = __builtin_amdgcn_mfma_f32_16x16x32_bf16(af2, bfw, acc2[nt], 0, 0, 0);
            }
        }
        float* Out = ws + ((mode == 0) ? OFF_ETQ : OFF_ETK);   // both row-major
        #pragma unroll
        for (int nt = 0; nt < 4; nt++) {
            int d = l16 + nt * 16;
            float bi = biasF[d];
            #pragma unroll
            for (int r = 0; r < 4; r++) {
                int l = lbase + quad * 4 + r;
                Out[(size_t)(bh * LSEQ + l) * 64 + d] =
                    __expf(2.f * (acc2[nt][r] + bi));
            }
        }
    }
}

// ---------------------------------------------------------------------------
// Kernel 2: additive attention, TQ=8, 384 threads (t = k). Etk row-major:
// thread t reads its Etk row via 16 b128 loads (deep MLP, L1 reuse).
// Energy (r14): PAIRED reciprocals with pre-scaled operands. Instead of
//   e2 += w_d * rcp(Etq*Etk + 1)           (1 rcp per d — trans-pipe bound,
//                                            v_rcp_f32 is quarter-rate)
// we precompute Etq' = Etq/w_d, c_d = 1/w_d so u_d = fma(Etq',Ek,c_d)
//   = (x_d+1)/w_d, and per PAIR: 1/u1 + 1/u2 = (u1+u2)*rcp(u1*u2).
// r16/r17 post-mortem: further VALU/trans algebra (4-way grouping, packed
// fp32) is NULL or WRONG — after r14 the loop is mixed VALU/LDS-issue
// bound; per-thread LDS reads (128 b128) are already the structural floor.
// NOTE (r13 post-mortem): do NOT add per-thread arrays to the energy loop —
// under __launch_bounds__(384,6) they spill to scratch (372 MB FETCH, 3x dur).
// ---------------------------------------------------------------------------
__global__ __launch_bounds__(384, 6) void attn_kernel(
    const void* qp, const void* vwp, const void* vbp,
    const float* __restrict__ ws_in, float* __restrict__ ws,
    const int* __restrict__ mask, void* __restrict__ dout)
{
    __shared__ int s_cnt;
    const int f = block_detect((const unsigned int*)qp, &s_cnt);

    const float* Etq = ws_in + OFF_ETQ;
    const float* Etk = ws_in + OFF_ETK;
    const float* Vh  = ws_in + OFF_VH;
    float* Xh = ws + OFF_XH;

    const int bid = blockIdx.x;
    const int qt = bid % QTILES;
    const int bh = bid / QTILES;
    const int q0 = qt * TQ;
    const int b  = bh >> 3;
    const int h  = bh & 7;
    const int t  = threadIdx.x;
    const int wave = t >> 6;

    __shared__ __align__(16) float etq8[64][TQ];   // Etq / w_d
    __shared__ float cws[64];                       // 1 / w_d
    __shared__ float ps[TQ][LSEQ];
    __shared__ float red[6][TQ][16][4];
    __shared__ float rsum[TQ][6];
    __shared__ float s_vb;

    for (int i = t; i < TQ * 64; i += 384) {
        int qi = i >> 6, d = i & 63;
        float wv = ld1(vwp, d, f);
        etq8[d][qi] = Etq[(size_t)(bh * LSEQ + q0 + qi) * 64 + d] / wv;
    }
    if (t < 64) {
        float v = ld1(vwp, t, f);
        cws[t] = 1.0f / v;
        #pragma unroll
        for (int off = 32; off > 0; off >>= 1) v += __shfl_xor(v, off, 64);
        if (t == 0) s_vb = ld1(vbp, 0, f) + v;
    }
    const int mok = mask[b * LSEQ + t];
    __syncthreads();
    const float vbSum = s_vb;

    float e2[TQ] = {0.f, 0.f, 0.f, 0.f, 0.f, 0.f, 0.f, 0.f};
    const float* ekrow = Etk + (size_t)(bh * LSEQ + t) * 64;
    #pragma unroll 4
    for (int dv = 0; dv < 16; dv++) {
        float4 ek4 = *reinterpret_cast<const float4*>(ekrow + dv * 4);
        #pragma unroll
        for (int pj = 0; pj < 2; pj++) {
            const int d0 = dv * 4 + pj * 2;
            const float ekA = pj ? ek4.z : ek4.x;
            const float ekB = pj ? ek4.w : ek4.y;
            const float cA = cws[d0];
            const float cB = cws[d0 + 1];
            float4 qA0 = *reinterpret_cast<const float4*>(&etq8[d0][0]);
            float4 qA1 = *reinterpret_cast<const float4*>(&etq8[d0][4]);
            float4 qB0 = *reinterpret_cast<const float4*>(&etq8[d0 + 1][0]);
            float4 qB1 = *reinterpret_cast<const float4*>(&etq8[d0 + 1][4]);
            {
                float u1 = fmaf(qA0.x, ekA, cA), u2 = fmaf(qB0.x, ekB, cB);
                e2[0] = fmaf(u1 + u2, __builtin_amdgcn_rcpf(u1 * u2), e2[0]);
            }
            {
                float u1 = fmaf(qA0.y, ekA, cA), u2 = fmaf(qB0.y, ekB, cB);
                e2[1] = fmaf(u1 + u2, __builtin_amdgcn_rcpf(u1 * u2), e2[1]);
            }
            {
                float u1 = fmaf(qA0.z, ekA, cA), u2 = fmaf(qB0.z, ekB, cB);
                e2[2] = fmaf(u1 + u2, __builtin_amdgcn_rcpf(u1 * u2), e2[2]);
            }
            {
                float u1 = fmaf(qA0.w, ekA, cA), u2 = fmaf(qB0.w, ekB, cB);
                e2[3] = fmaf(u1 + u2, __builtin_amdgcn_rcpf(u1 * u2), e2[3]);
            }
            {
                float u1 = fmaf(qA1.x, ekA, cA), u2 = fmaf(qB1.x, ekB, cB);
                e2[4] = fmaf(u1 + u2, __builtin_amdgcn_rcpf(u1 * u2), e2[4]);
            }
            {
                float u1 = fmaf(qA1.y, ekA, cA), u2 = fmaf(qB1.y, ekB, cB);
                e2[5] = fmaf(u1 + u2, __builtin_amdgcn_rcpf(u1 * u2), e2[5]);
            }
            {
                float u1 = fmaf(qA1.z, ekA, cA), u2 = fmaf(qB1.z, ekB, cB);
                e2[6] = fmaf(u1 + u2, __builtin_amdgcn_rcpf(u1 * u2), e2[6]);
            }
            {
                float u1 = fmaf(qA1.w, ekA, cA), u2 = fmaf(qB1.w, ekB, cB);
                e2[7] = fmaf(u1 + u2, __builtin_amdgcn_rcpf(u1 * u2), e2[7]);
            }
        }
    }

    float p[TQ];
    #pragma unroll
    for (int qi = 0; qi < TQ; qi++) {
        float en = fmaf(-2.0f, e2[qi], vbSum);
        if (mok == 0) en = -1e10f;
        p[qi] = __expf(en);
        float s = p[qi];
        #pragma unroll
        for (int off = 32; off > 0; off >>= 1) s += __shfl_xor(s, off, 64);
        if ((t & 63) == 0) rsum[qi][wave] = s;
    }
    __syncthreads();
    #pragma unroll
    for (int qi = 0; qi < TQ; qi++) {
        float gs = rsum[qi][0] + rsum[qi][1] + rsum[qi][2] +
                   rsum[qi][3] + rsum[qi][4] + rsum[qi][5];
        p[qi] *= 1.0f / gs;
        ps[qi][t] = p[qi];
        size_t aidx = XELEMS + (size_t)(bh * LSEQ + q0 + qi) * LSEQ + t;
        if (f) ((float*)dout)[aidx] = p[qi];
        else   ((ushort_t*)dout)[aidx] = f2bf(p[qi]);
    }
    __syncthreads();

    const int dq = t & 15;
    const int ksub = t >> 4;
    const float* vb4 = Vh + (size_t)bh * LSEQ * 64 + dq * 4;
    float4 acc[TQ];
    #pragma unroll
    for (int qi = 0; qi < TQ; qi++) acc[qi] = make_float4(0.f, 0.f, 0.f, 0.f);
    for (int kk = ksub; kk < LSEQ; kk += 24) {
        float4 v4 = *reinterpret_cast<const float4*>(vb4 + (size_t)kk * 64);
        #pragma unroll
        for (int qi = 0; qi < TQ; qi++) {
            float pq = ps[qi][kk];
            acc[qi].x = fmaf(pq, v4.x, acc[qi].x);
            acc[qi].y = fmaf(pq, v4.y, acc[qi].y);
            acc[qi].z = fmaf(pq, v4.z, acc[qi].z);
            acc[qi].w = fmaf(pq, v4.w, acc[qi].w);
        }
    }
    #pragma unroll
    for (int qi = 0; qi < TQ; qi++) {
        #pragma unroll
        for (int off = 16; off <= 32; off <<= 1) {
            acc[qi].x += __shfl_xor(acc[qi].x, off, 64);
            acc[qi].y += __shfl_xor(acc[qi].y, off, 64);
            acc[qi].z += __shfl_xor(acc[qi].z, off, 64);
            acc[qi].w += __shfl_xor(acc[qi].w, off, 64);
        }
    }
    if ((t & 63) < 16) {
        #pragma unroll
        for (int qi = 0; qi < TQ; qi++) {
            red[wave][qi][dq][0] = acc[qi].x;
            red[wave][qi][dq][1] = acc[qi].y;
            red[wave][qi][dq][2] = acc[qi].z;
            red[wave][qi][dq][3] = acc[qi].w;
        }
    }
    __syncthreads();
    if (t < 256) {
        int d = t & 63;
        #pragma unroll
        for (int half = 0; half < 2; half++) {
            int qi = (t >> 6) + half * 4;
            float sx = 0.f;
            #pragma unroll
            for (int w = 0; w < 6; w++) sx += red[w][qi][d >> 2][d & 3];
            Xh[((size_t)(b * LSEQ + q0 + qi) * NH + h) * 64 + d] = sx;
        }
    }
}

// ---------------------------------------------------------------------------
// Kernel 3: output projection via bf16 MFMA. x = Xh @ Wo^T + bo, dual-dtype.
// ---------------------------------------------------------------------------
__global__ __launch_bounds__(128) void gemm_out(
    const void* qp, const void* Wop, const void* bop,
    const float* __restrict__ ws_in, void* __restrict__ dout)
{
    __shared__ int s_cnt;
    __shared__ ushort_t smA[32 * LDSTR];
    __shared__ ushort_t smB[64 * LDSTR];
    __shared__ float biasF[64];
    const int f = block_detect((const unsigned int*)qp, &s_cnt);

    const float* Xh = ws_in + OFF_XH;
    const int col0 = blockIdx.x * 64;
    const int row0 = blockIdx.y * 32;
    const int t = threadIdx.x;
    const int w = t >> 6, l16 = t & 15, quad = (t & 63) >> 4;

    if (t < 64) biasF[t] = ld1(bop, col0 + t, f);

    const int arow = t >> 2, acol = (t & 3) * 16;
    const int brow = t >> 1, bcol = (t & 1) * 32;
    const float* Ab = Xh + (size_t)(row0 + arow) * 512 + acol;
    const size_t bbase = (size_t)(col0 + brow) * 512 + bcol;

    float4 a4[4], b4[8];
    #pragma unroll
    for (int i = 0; i < 4; i++) a4[i] = *reinterpret_cast<const float4*>(Ab + i * 4);
    #pragma unroll
    for (int i = 0; i < 8; i++) b4[i] = ld4(Wop, bbase + i * 4, f);

    f32x4 acc[4];
    #pragma unroll
    for (int nt = 0; nt < 4; nt++) acc[nt] = (f32x4){0.f, 0.f, 0.f, 0.f};

    for (int k0 = 0; k0 < 512; k0 += 64) {
        __syncthreads();
        *reinterpret_cast<uint4*>(&smA[arow * LDSTR + acol])     = packu4(a4[0], a4[1]);
        *reinterpret_cast<uint4*>(&smA[arow * LDSTR + acol + 8]) = packu4(a4[2], a4[3]);
        *reinterpret_cast<uint4*>(&smB[brow * LDSTR + bcol])      = packu4(b4[0], b4[1]);
        *reinterpret_cast<uint4*>(&smB[brow * LDSTR + bcol + 8])  = packu4(b4[2], b4[3]);
        *reinterpret_cast<uint4*>(&smB[brow * LDSTR + bcol + 16]) = packu4(b4[4], b4[5]);
        *reinterpret_cast<uint4*>(&smB[brow * LDSTR + bcol + 24]) = packu4(b4[6], b4[7]);
        __syncthreads();
        if (k0 + 64 < 512) {
            #pragma unroll
            for (int i = 0; i < 4; i++)
                a4[i] = *reinterpret_cast<const float4*>(Ab + k0 + 64 + i * 4);
            #pragma unroll
            for (int i = 0; i < 8; i++) b4[i] = ld4(Wop, bbase + k0 + 64 + i * 4, f);
        }
        #pragma unroll
        for (int kk = 0; kk < 2; kk++) {
            bf16x8 af = *reinterpret_cast<const bf16x8*>(
                &smA[(w * 16 + l16) * LDSTR + kk * 32 + quad * 8]);
            #pragma unroll
            for (int nt = 0; nt < 4; nt++) {
                bf16x8 bfr = *reinterpret_cast<const bf16x8*>(
                    &smB[(nt * 16 + l16) * LDSTR + kk * 32 + quad * 8]);
                acc[nt] = __builtin_amdgcn_mfma_f32_16x16x32_bf16(af, bfr, acc[nt], 0, 0, 0);
            }
        }
    }

    #pragma unroll
    for (int nt = 0; nt < 4; nt++) {
        int n = col0 + l16 + nt * 16;
        float bi = biasF[l16 + nt * 16];
        #pragma unroll
        for (int r = 0; r < 4; r++) {
            int m = row0 + w * 16 + quad * 4 + r;
            float c = acc[nt][r] + bi;
            size_t idx = (size_t)m * 512 + n;
            if (f) ((float*)dout)[idx] = c;
            else   ((ushort_t*)dout)[idx] = f2bf(c);
        }
    }
}

// ---------------------------------------------------------------------------
extern "C" void kernel_launch(void* const* d_in, const int* in_sizes, int n_in,
                              void* d_out, int out_size, void* d_ws, size_t ws_size,
                              hipStream_t stream)
{
    const void* qp = d_in[0];
    const void* kp = d_in[1];
    const void* vp = d_in[2];
    const int* mask = (const int*)d_in[3];
    const void* Wqp = d_in[4];  const void* bqp = d_in[5];
    const void* Wkp = d_in[6];  const void* bkp = d_in[7];
    const void* Wvp = d_in[8];  const void* bvp = d_in[9];
    const void* Wop = d_in[10]; const void* bop = d_in[11];
    const void* W1p = d_in[12]; const void* b1p = d_in[13];
    const void* W2p = d_in[14]; const void* b2p = d_in[15];
    const void* vwp = d_in[16]; const void* vbp = d_in[17];

    float* ws = (float*)d_ws;

    gemm_qkv<<<dim3(8, 24, 3), 128, 0, stream>>>(qp, kp, vp, Wqp, Wkp, Wvp,
                                                 W1p, W2p, bqp, bkp, b1p, b2p,
                                                 bvp, ws);
    attn_kernel<<<BH * QTILES, 384, 0, stream>>>(qp, vwp, vbp, ws, ws, mask, d_out);
    gemm_out<<<dim3(8, 24, 1), 128, 0, stream>>>(qp, Wop, bop, ws, d_out);
}

// Round 7
// 158.754 us; speedup vs baseline: 1.0185x; 1.0022x over previous
//
#include <hip/hip_runtime.h>

// Problem constants
#define BATCH 2
#define LSEQ 384
#define NHID 512
#define NH 8
#define DH 64
#define BH (BATCH*NH)          // 16
#define XELEMS ((size_t)768 * NHID)        // 393216 (x output elems)
#define TQ 8                   // q-rows per attn block
#define QTILES (LSEQ/TQ)       // 48

typedef unsigned short ushort_t;
typedef __attribute__((ext_vector_type(8))) short bf16x8;
typedef __attribute__((ext_vector_type(4))) float f32x4;

__device__ __forceinline__ float bf2f(ushort_t u) {
    unsigned int v = ((unsigned int)u) << 16;
    return __uint_as_float(v);
}
__device__ __forceinline__ ushort_t f2bf(float f) {
    unsigned int u = __float_as_uint(f);
    unsigned int lsb = (u >> 16) & 1u;
    u += 0x7fffu + lsb;           // round-to-nearest-even
    return (ushort_t)(u >> 16);
}
// RNE bf16 pair-pack: 2x add + v_perm (ushort0=bf16(a), ushort1=bf16(b))
__device__ __forceinline__ unsigned pk_bf16(float a, float b) {
    unsigned ua = __float_as_uint(a), ub = __float_as_uint(b);
    ua += 0x7fffu + ((ua >> 16) & 1u);
    ub += 0x7fffu + ((ub >> 16) & 1u);
    return __builtin_amdgcn_perm(ub, ua, 0x07060302);
}
__device__ __forceinline__ float ld1(const void* p, size_t i, int f) {
    return f ? ((const float*)p)[i] : bf2f(((const ushort_t*)p)[i]);
}
__device__ __forceinline__ float4 ld4(const void* p, size_t i, int f) {
    if (f) return ((const float4*)p)[i >> 2];
    ushort4 u = ((const ushort4*)p)[i >> 2];
    return make_float4(bf2f(u.x), bf2f(u.y), bf2f(u.z), bf2f(u.w));
}
__device__ __forceinline__ int block_detect(const unsigned int* q, int* cnt) {
    int t = threadIdx.x;
    if (t == 0) *cnt = 0;
    __syncthreads();
    int n = blockDim.x < 256 ? blockDim.x : 256;
    if (t < n) {
        unsigned int elo = (q[t] >> 7) & 0xFFu;
        if (elo >= 100u && elo <= 150u) atomicAdd(cnt, 1);
    }
    __syncthreads();
    return (*cnt * 2 > n) ? 0 : 1;     // 0 = bf16-packed, 1 = fp32
}
__device__ __forceinline__ uint4 packu4(float4 a, float4 b) {
    uint4 r;
    r.x = pk_bf16(a.x, a.y); r.y = pk_bf16(a.z, a.w);
    r.z = pk_bf16(b.x, b.y); r.w = pk_bf16(b.z, b.w);
    return r;
}
__device__ __forceinline__ bf16x8 pack_bf8(float4 a, float4 b) {
    union { uint4 u; bf16x8 v; } r;
    r.u = packu4(a, b);
    return r.v;
}

// ---------------- workspace layout (float offsets) ----------------
#define OFF_ETQ   16                  // Etq = exp(2 tq)  [bh][l][d]
#define OFF_ETK   (16 + 393216)       // Etk = exp(2 tk)  [bh][l][d] (row-major)
#define OFF_VH    (16 + 2*393216)     // V                [bh][l][d]
#define OFF_XH    (16 + 3*393216)     // context [B,L,H,D]

#define LDSTR 72   // LDS row stride in ushorts (144 B)

// ---------------------------------------------------------------------------
// Kernel 1: QKV projection via bf16 MFMA. 32(m) x 64(n=head) tile, 128 thr
// (2 waves), K=512 step 64, reg prefetch. Modes 0/1 fold W1/W2 via a second
// in-register MFMA pass and write Etq/Etk = exp(2(..+biasF)) row-major;
// mode 2 writes V + bv.
// r15 NOTE: in-block split-K x2 (256 thr) REGRESSED +2.5us — kernels are
// only ~2-4us; extra syncs + LDS reduce cost more than latency saved.
// r17/r19 NOTE: VOP3P v_pk_* via inline asm FAILED numerics twice with
// IDENTICAL absmax (3.7e-2), with and without explicit op_sel/op_sel_hi —
// the encoding route is closed on this harness (no disasm to debug).
// r18: bias fold vectorized (ld4 pairs, 16 iters) — neutral but kept.
// ---------------------------------------------------------------------------
__global__ __launch_bounds__(128) void gemm_qkv(
    const void* qp, const void* kp, const void* vp,
    const void* Wqp, const void* Wkp, const void* Wvp,
    const void* W1p, const void* W2p,
    const void* bqp, const void* bkp, const void* b1p, const void* b2p,
    const void* bvp, float* __restrict__ ws)
{
    __shared__ int s_cnt;
    __shared__ ushort_t smA[32 * LDSTR];
    __shared__ ushort_t smB[64 * LDSTR];
    __shared__ float biasF[64];
    const int f = block_detect((const unsigned int*)qp, &s_cnt);

    const int mode = blockIdx.z;
    const void* A = (mode == 0) ? qp : (mode == 1) ? kp : vp;
    const void* W = (mode == 0) ? Wqp : (mode == 1) ? Wkp : Wvp;
    const void* W1x = (mode == 1) ? W2p : W1p;

    const int h    = blockIdx.x;
    const int col0 = h * 64;
    const int row0 = blockIdx.y * 32;
    const int t = threadIdx.x;
    const int w = t >> 6, l16 = t & 15, quad = (t & 63) >> 4;

    // fused bias into LDS (threads 0..63), overlapped with prefetch
    if (t < 64) {
        if (mode == 2) {
            biasF[t] = ld1(bvp, col0 + t, f);
        } else {
            const void* b1x = (mode == 1) ? b2p : b1p;
            const void* bx  = (mode == 1) ? bkp : bqp;
            float s = ld1(b1x, t, f);
            for (int j = 0; j < 64; j += 4) {
                float4 wv = ld4(W1x, (size_t)t * 64 + j, f);
                float4 bv = ld4(bx, (size_t)h * 64 + j, f);
                s = fmaf(wv.x, bv.x, s);
                s = fmaf(wv.y, bv.y, s);
                s = fmaf(wv.z, bv.z, s);
                s = fmaf(wv.w, bv.w, s);
            }
            biasF[t] = s;
        }
    }

    const int arow = t >> 2, acol = (t & 3) * 16;
    const int brow = t >> 1, bcol = (t & 1) * 32;
    const size_t abase = (size_t)(row0 + arow) * 512 + acol;
    const size_t bbase = (size_t)(col0 + brow) * 512 + bcol;

    float4 a4[4], b4[8];
    #pragma unroll
    for (int i = 0; i < 4; i++) a4[i] = ld4(A, abase + i * 4, f);
    #pragma unroll
    for (int i = 0; i < 8; i++) b4[i] = ld4(W, bbase + i * 4, f);

    f32x4 acc[4];
    #pragma unroll
    for (int nt = 0; nt < 4; nt++) acc[nt] = (f32x4){0.f, 0.f, 0.f, 0.f};

    for (int k0 = 0; k0 < 512; k0 += 64) {
        __syncthreads();
        *reinterpret_cast<uint4*>(&smA[arow * LDSTR + acol])     = packu4(a4[0], a4[1]);
        *reinterpret_cast<uint4*>(&smA[arow * LDSTR + acol + 8]) = packu4(a4[2], a4[3]);
        *reinterpret_cast<uint4*>(&smB[brow * LDSTR + bcol])      = packu4(b4[0], b4[1]);
        *reinterpret_cast<uint4*>(&smB[brow * LDSTR + bcol + 8])  = packu4(b4[2], b4[3]);
        *reinterpret_cast<uint4*>(&smB[brow * LDSTR + bcol + 16]) = packu4(b4[4], b4[5]);
        *reinterpret_cast<uint4*>(&smB[brow * LDSTR + bcol + 24]) = packu4(b4[6], b4[7]);
        __syncthreads();
        if (k0 + 64 < 512) {
            #pragma unroll
            for (int i = 0; i < 4; i++) a4[i] = ld4(A, abase + k0 + 64 + i * 4, f);
            #pragma unroll
            for (int i = 0; i < 8; i++) b4[i] = ld4(W, bbase + k0 + 64 + i * 4, f);
        }
        #pragma unroll
        for (int kk = 0; kk < 2; kk++) {
            bf16x8 af = *reinterpret_cast<const bf16x8*>(
                &smA[(w * 16 + l16) * LDSTR + kk * 32 + quad * 8]);
            #pragma unroll
            for (int nt = 0; nt < 4; nt++) {
                bf16x8 bfr = *reinterpret_cast<const bf16x8*>(
                    &smB[(nt * 16 + l16) * LDSTR + kk * 32 + quad * 8]);
                acc[nt] = __builtin_amdgcn_mfma_f32_16x16x32_bf16(af, bfr, acc[nt], 0, 0, 0);
            }
        }
    }

    const int b  = (row0 >= LSEQ) ? 1 : 0;
    const int lbase = row0 - b * LSEQ + w * 16;
    const int bh = b * NH + h;

    if (mode == 2) {
        float* Out = ws + OFF_VH;
        #pragma unroll
        for (int nt = 0; nt < 4; nt++) {
            int d = l16 + nt * 16;
            float bi = biasF[d];
            #pragma unroll
            for (int r = 0; r < 4; r++) {
                int l = lbase + quad * 4 + r;
                Out[(size_t)(bh * LSEQ + l) * 64 + d] = acc[nt][r] + bi;
            }
        }
    } else {
        // ---- fold: restage acc (bf16) in wave-private LDS rows, x W1^T ----
        #pragma unroll
        for (int nt = 0; nt < 4; nt++)
            #pragma unroll
            for (int r = 0; r < 4; r++)
                smA[(w * 16 + quad * 4 + r) * LDSTR + l16 + nt * 16] =
                    f2bf(acc[nt][r]);
        f32x4 acc2[4];
        #pragma unroll
        for (int nt = 0; nt < 4; nt++) acc2[nt] = (f32x4){0.f, 0.f, 0.f, 0.f};
        #pragma unroll
        for (int kk = 0; kk < 2; kk++) {
            bf16x8 af2 = *reinterpret_cast<const bf16x8*>(
                &smA[(w * 16 + l16) * LDSTR + kk * 32 + quad * 8]);
            #pragma unroll
            for (int nt = 0; nt < 4; nt++) {
                int od = nt * 16 + l16, j0 = kk * 32 + quad * 8;
                float4 wa = ld4(W1x, (size_t)od * 64 + j0, f);
                float4 wb = ld4(W1x, (size_t)od * 64 + j0 + 4, f);
                bf16x8 bfw = pack_bf8(wa, wb);
                acc2[nt] = __builtin_amdgcn_mfma_f32_16x16x32_bf16(af2, bfw, acc2[nt], 0, 0, 0);
            }
        }
        float* Out = ws + ((mode == 0) ? OFF_ETQ : OFF_ETK);   // both row-major
        #pragma unroll
        for (int nt = 0; nt < 4; nt++) {
            int d = l16 + nt * 16;
            float bi = biasF[d];
            #pragma unroll
            for (int r = 0; r < 4; r++) {
                int l = lbase + quad * 4 + r;
                Out[(size_t)(bh * LSEQ + l) * 64 + d] =
                    __expf(2.f * (acc2[nt][r] + bi));
            }
        }
    }
}

// ---------------------------------------------------------------------------
// Kernel 2: additive attention, TQ=8, 384 threads (t = k). Etk row-major:
// thread t reads its Etk row via 16 b128 loads (deep MLP, L1 reuse).
// Energy (r14): PAIRED reciprocals with pre-scaled operands. Instead of
//   e2 += w_d * rcp(Etq*Etk + 1)           (1 rcp per d — trans-pipe bound,
//                                            v_rcp_f32 is quarter-rate)
// we precompute Etq' = Etq/w_d, c_d = 1/w_d so u_d = fma(Etq',Ek,c_d)
//   = (x_d+1)/w_d, and per PAIR: 1/u1 + 1/u2 = (u1+u2)*rcp(u1*u2).
// Pair-form is the VALU-optimal scalar formulation (2.5 instr/unit; r16's
// 4-way = 2.75, null). Packed fp32 (v_pk_*) failed numerics twice via asm
// (r17/r19, identical absmax) — closed. Energy is now balanced across
// VALU (~4.8us/SIMD), trans (~3.8us), broadcast-LDS issue — no single
// dominant pipe remains.
// NOTE (r13 post-mortem): do NOT add per-thread arrays to the energy loop —
// under __launch_bounds__(384,6) they spill to scratch (372 MB FETCH, 3x dur).
// ---------------------------------------------------------------------------
__global__ __launch_bounds__(384, 6) void attn_kernel(
    const void* qp, const void* vwp, const void* vbp,
    const float* __restrict__ ws_in, float* __restrict__ ws,
    const int* __restrict__ mask, void* __restrict__ dout)
{
    __shared__ int s_cnt;
    const int f = block_detect((const unsigned int*)qp, &s_cnt);

    const float* Etq = ws_in + OFF_ETQ;
    const float* Etk = ws_in + OFF_ETK;
    const float* Vh  = ws_in + OFF_VH;
    float* Xh = ws + OFF_XH;

    const int bid = blockIdx.x;
    const int qt = bid % QTILES;
    const int bh = bid / QTILES;
    const int q0 = qt * TQ;
    const int b  = bh >> 3;
    const int h  = bh & 7;
    const int t  = threadIdx.x;
    const int wave = t >> 6;

    __shared__ __align__(16) float etq8[64][TQ];   // Etq / w_d
    __shared__ float cws[64];                       // 1 / w_d
    __shared__ float ps[TQ][LSEQ];
    __shared__ float red[6][TQ][16][4];
    __shared__ float rsum[TQ][6];
    __shared__ float s_vb;

    for (int i = t; i < TQ * 64; i += 384) {
        int qi = i >> 6, d = i & 63;
        float wv = ld1(vwp, d, f);
        etq8[d][qi] = Etq[(size_t)(bh * LSEQ + q0 + qi) * 64 + d] / wv;
    }
    if (t < 64) {
        float v = ld1(vwp, t, f);
        cws[t] = 1.0f / v;
        #pragma unroll
        for (int off = 32; off > 0; off >>= 1) v += __shfl_xor(v, off, 64);
        if (t == 0) s_vb = ld1(vbp, 0, f) + v;
    }
    const int mok = mask[b * LSEQ + t];
    __syncthreads();
    const float vbSum = s_vb;

    float e2[TQ] = {0.f, 0.f, 0.f, 0.f, 0.f, 0.f, 0.f, 0.f};
    const float* ekrow = Etk + (size_t)(bh * LSEQ + t) * 64;
    #pragma unroll 4
    for (int dv = 0; dv < 16; dv++) {
        float4 ek4 = *reinterpret_cast<const float4*>(ekrow + dv * 4);
        #pragma unroll
        for (int pj = 0; pj < 2; pj++) {
            const int d0 = dv * 4 + pj * 2;
            const float ekA = pj ? ek4.z : ek4.x;
            const float ekB = pj ? ek4.w : ek4.y;
            const float cA = cws[d0];
            const float cB = cws[d0 + 1];
            float4 qA0 = *reinterpret_cast<const float4*>(&etq8[d0][0]);
            float4 qA1 = *reinterpret_cast<const float4*>(&etq8[d0][4]);
            float4 qB0 = *reinterpret_cast<const float4*>(&etq8[d0 + 1][0]);
            float4 qB1 = *reinterpret_cast<const float4*>(&etq8[d0 + 1][4]);
            {
                float u1 = fmaf(qA0.x, ekA, cA), u2 = fmaf(qB0.x, ekB, cB);
                e2[0] = fmaf(u1 + u2, __builtin_amdgcn_rcpf(u1 * u2), e2[0]);
            }
            {
                float u1 = fmaf(qA0.y, ekA, cA), u2 = fmaf(qB0.y, ekB, cB);
                e2[1] = fmaf(u1 + u2, __builtin_amdgcn_rcpf(u1 * u2), e2[1]);
            }
            {
                float u1 = fmaf(qA0.z, ekA, cA), u2 = fmaf(qB0.z, ekB, cB);
                e2[2] = fmaf(u1 + u2, __builtin_amdgcn_rcpf(u1 * u2), e2[2]);
            }
            {
                float u1 = fmaf(qA0.w, ekA, cA), u2 = fmaf(qB0.w, ekB, cB);
                e2[3] = fmaf(u1 + u2, __builtin_amdgcn_rcpf(u1 * u2), e2[3]);
            }
            {
                float u1 = fmaf(qA1.x, ekA, cA), u2 = fmaf(qB1.x, ekB, cB);
                e2[4] = fmaf(u1 + u2, __builtin_amdgcn_rcpf(u1 * u2), e2[4]);
            }
            {
                float u1 = fmaf(qA1.y, ekA, cA), u2 = fmaf(qB1.y, ekB, cB);
                e2[5] = fmaf(u1 + u2, __builtin_amdgcn_rcpf(u1 * u2), e2[5]);
            }
            {
                float u1 = fmaf(qA1.z, ekA, cA), u2 = fmaf(qB1.z, ekB, cB);
                e2[6] = fmaf(u1 + u2, __builtin_amdgcn_rcpf(u1 * u2), e2[6]);
            }
            {
                float u1 = fmaf(qA1.w, ekA, cA), u2 = fmaf(qB1.w, ekB, cB);
                e2[7] = fmaf(u1 + u2, __builtin_amdgcn_rcpf(u1 * u2), e2[7]);
            }
        }
    }

    float p[TQ];
    #pragma unroll
    for (int qi = 0; qi < TQ; qi++) {
        float en = fmaf(-2.0f, e2[qi], vbSum);
        if (mok == 0) en = -1e10f;
        p[qi] = __expf(en);
        float s = p[qi];
        #pragma unroll
        for (int off = 32; off > 0; off >>= 1) s += __shfl_xor(s, off, 64);
        if ((t & 63) == 0) rsum[qi][wave] = s;
    }
    __syncthreads();
    #pragma unroll
    for (int qi = 0; qi < TQ; qi++) {
        float gs = rsum[qi][0] + rsum[qi][1] + rsum[qi][2] +
                   rsum[qi][3] + rsum[qi][4] + rsum[qi][5];
        p[qi] *= 1.0f / gs;
        ps[qi][t] = p[qi];
        size_t aidx = XELEMS + (size_t)(bh * LSEQ + q0 + qi) * LSEQ + t;
        if (f) ((float*)dout)[aidx] = p[qi];
        else   ((ushort_t*)dout)[aidx] = f2bf(p[qi]);
    }
    __syncthreads();

    const int dq = t & 15;
    const int ksub = t >> 4;
    const float* vb4 = Vh + (size_t)bh * LSEQ * 64 + dq * 4;
    float4 acc[TQ];
    #pragma unroll
    for (int qi = 0; qi < TQ; qi++) acc[qi] = make_float4(0.f, 0.f, 0.f, 0.f);
    for (int kk = ksub; kk < LSEQ; kk += 24) {
        float4 v4 = *reinterpret_cast<const float4*>(vb4 + (size_t)kk * 64);
        #pragma unroll
        for (int qi = 0; qi < TQ; qi++) {
            float pq = ps[qi][kk];
            acc[qi].x = fmaf(pq, v4.x, acc[qi].x);
            acc[qi].y = fmaf(pq, v4.y, acc[qi].y);
            acc[qi].z = fmaf(pq, v4.z, acc[qi].z);
            acc[qi].w = fmaf(pq, v4.w, acc[qi].w);
        }
    }
    #pragma unroll
    for (int qi = 0; qi < TQ; qi++) {
        #pragma unroll
        for (int off = 16; off <= 32; off <<= 1) {
            acc[qi].x += __shfl_xor(acc[qi].x, off, 64);
            acc[qi].y += __shfl_xor(acc[qi].y, off, 64);
            acc[qi].z += __shfl_xor(acc[qi].z, off, 64);
            acc[qi].w += __shfl_xor(acc[qi].w, off, 64);
        }
    }
    if ((t & 63) < 16) {
        #pragma unroll
        for (int qi = 0; qi < TQ; qi++) {
            red[wave][qi][dq][0] = acc[qi].x;
            red[wave][qi][dq][1] = acc[qi].y;
            red[wave][qi][dq][2] = acc[qi].z;
            red[wave][qi][dq][3] = acc[qi].w;
        }
    }
    __syncthreads();
    if (t < 256) {
        int d = t & 63;
        #pragma unroll
        for (int half = 0; half < 2; half++) {
            int qi = (t >> 6) + half * 4;
            float sx = 0.f;
            #pragma unroll
            for (int w = 0; w < 6; w++) sx += red[w][qi][d >> 2][d & 3];
            Xh[((size_t)(b * LSEQ + q0 + qi) * NH + h) * 64 + d] = sx;
        }
    }
}

// ---------------------------------------------------------------------------
// Kernel 3: output projection via bf16 MFMA. x = Xh @ Wo^T + bo, dual-dtype.
// ---------------------------------------------------------------------------
__global__ __launch_bounds__(128) void gemm_out(
    const void* qp, const void* Wop, const void* bop,
    const float* __restrict__ ws_in, void* __restrict__ dout)
{
    __shared__ int s_cnt;
    __shared__ ushort_t smA[32 * LDSTR];
    __shared__ ushort_t smB[64 * LDSTR];
    __shared__ float biasF[64];
    const int f = block_detect((const unsigned int*)qp, &s_cnt);

    const float* Xh = ws_in + OFF_XH;
    const int col0 = blockIdx.x * 64;
    const int row0 = blockIdx.y * 32;
    const int t = threadIdx.x;
    const int w = t >> 6, l16 = t & 15, quad = (t & 63) >> 4;

    if (t < 64) biasF[t] = ld1(bop, col0 + t, f);

    const int arow = t >> 2, acol = (t & 3) * 16;
    const int brow = t >> 1, bcol = (t & 1) * 32;
    const float* Ab = Xh + (size_t)(row0 + arow) * 512 + acol;
    const size_t bbase = (size_t)(col0 + brow) * 512 + bcol;

    float4 a4[4], b4[8];
    #pragma unroll
    for (int i = 0; i < 4; i++) a4[i] = *reinterpret_cast<const float4*>(Ab + i * 4);
    #pragma unroll
    for (int i = 0; i < 8; i++) b4[i] = ld4(Wop, bbase + i * 4, f);

    f32x4 acc[4];
    #pragma unroll
    for (int nt = 0; nt < 4; nt++) acc[nt] = (f32x4){0.f, 0.f, 0.f, 0.f};

    for (int k0 = 0; k0 < 512; k0 += 64) {
        __syncthreads();
        *reinterpret_cast<uint4*>(&smA[arow * LDSTR + acol])     = packu4(a4[0], a4[1]);
        *reinterpret_cast<uint4*>(&smA[arow * LDSTR + acol + 8]) = packu4(a4[2], a4[3]);
        *reinterpret_cast<uint4*>(&smB[brow * LDSTR + bcol])      = packu4(b4[0], b4[1]);
        *reinterpret_cast<uint4*>(&smB[brow * LDSTR + bcol + 8])  = packu4(b4[2], b4[3]);
        *reinterpret_cast<uint4*>(&smB[brow * LDSTR + bcol + 16]) = packu4(b4[4], b4[5]);
        *reinterpret_cast<uint4*>(&smB[brow * LDSTR + bcol + 24]) = packu4(b4[6], b4[7]);
        __syncthreads();
        if (k0 + 64 < 512) {
            #pragma unroll
            for (int i = 0; i < 4; i++)
                a4[i] = *reinterpret_cast<const float4*>(Ab + k0 + 64 + i * 4);
            #pragma unroll
            for (int i = 0; i < 8; i++) b4[i] = ld4(Wop, bbase + k0 + 64 + i * 4, f);
        }
        #pragma unroll
        for (int kk = 0; kk < 2; kk++) {
            bf16x8 af = *reinterpret_cast<const bf16x8*>(
                &smA[(w * 16 + l16) * LDSTR + kk * 32 + quad * 8]);
            #pragma unroll
            for (int nt = 0; nt < 4; nt++) {
                bf16x8 bfr = *reinterpret_cast<const bf16x8*>(
                    &smB[(nt * 16 + l16) * LDSTR + kk * 32 + quad * 8]);
                acc[nt] = __builtin_amdgcn_mfma_f32_16x16x32_bf16(af, bfr, acc[nt], 0, 0, 0);
            }
        }
    }

    #pragma unroll
    for (int nt = 0; nt < 4; nt++) {
        int n = col0 + l16 + nt * 16;
        float bi = biasF[l16 + nt * 16];
        #pragma unroll
        for (int r = 0; r < 4; r++) {
            int m = row0 + w * 16 + quad * 4 + r;
            float c = acc[nt][r] + bi;
            size_t idx = (size_t)m * 512 + n;
            if (f) ((float*)dout)[idx] = c;
            else   ((ushort_t*)dout)[idx] = f2bf(c);
        }
    }
}

// ---------------------------------------------------------------------------
extern "C" void kernel_launch(void* const* d_in, const int* in_sizes, int n_in,
                              void* d_out, int out_size, void* d_ws, size_t ws_size,
                              hipStream_t stream)
{
    const void* qp = d_in[0];
    const void* kp = d_in[1];
    const void* vp = d_in[2];
    const int* mask = (const int*)d_in[3];
    const void* Wqp = d_in[4];  const void* bqp = d_in[5];
    const void* Wkp = d_in[6];  const void* bkp = d_in[7];
    const void* Wvp = d_in[8];  const void* bvp = d_in[9];
    const void* Wop = d_in[10]; const void* bop = d_in[11];
    const void* W1p = d_in[12]; const void* b1p = d_in[13];
    const void* W2p = d_in[14]; const void* b2p = d_in[15];
    const void* vwp = d_in[16]; const void* vbp = d_in[17];

    float* ws = (float*)d_ws;

    gemm_qkv<<<dim3(8, 24, 3), 128, 0, stream>>>(qp, kp, vp, Wqp, Wkp, Wvp,
                                                 W1p, W2p, bqp, bkp, b1p, b2p,
                                                 bvp, ws);
    attn_kernel<<<BH * QTILES, 384, 0, stream>>>(qp, vwp, vbp, ws, ws, mask, d_out);
    gemm_out<<<dim3(8, 24, 1), 128, 0, stream>>>(qp, Wop, bop, ws, d_out);
}